// Round 13
// baseline (826.819 us; speedup 1.0000x reference)
//
#include <hip/hip_runtime.h>
#include <math.h>

#define CDIM 384
#define SDIM 4096
#define BDIM 4
#define DINC 768
#define NST  16
#define NCHUNK 64
#define LCHUNK 64
#define PSTRIDE 6291456   // ELEMENTS per conv partial [B,C,S] (bf16)

typedef unsigned short ushort_t;
typedef unsigned int uint_t;
typedef __attribute__((ext_vector_type(4))) float f32x4;
typedef __attribute__((ext_vector_type(8))) short bf16x8;

__device__ __forceinline__ ushort_t f2bf(float f) {
    union { float f; uint_t u; } v; v.f = f;
    uint_t r = v.u + 0x7FFFu + ((v.u >> 16) & 1u);   // round-to-nearest-even
    return (ushort_t)(r >> 16);
}
__device__ __forceinline__ float bf2f(ushort_t u) {
    union { uint_t i; float f; } v; v.i = ((uint_t)u) << 16; return v.f;
}
__device__ __forceinline__ uint_t pk2(float a, float b) {
    return (uint_t)f2bf(a) | ((uint_t)f2bf(b) << 16);
}
// async global->LDS, 16B per lane, dest = wave-uniform base + lane*16
__device__ __forceinline__ void gl16(const ushort_t* g, ushort_t* l) {
    __builtin_amdgcn_global_load_lds(
        (const __attribute__((address_space(1))) void*)(g),
        (__attribute__((address_space(3))) void*)(l), 16, 0, 0);
}

// ---------------------------------------------------------------------------
// Merged weight prep: all fp32->bf16 weight conversions in one dispatch.
// ---------------------------------------------------------------------------
__device__ __forceinline__ void wconv_body(const float* __restrict__ W,
                                           ushort_t* __restrict__ Wb, int idx) {
    const float* wp = W + (size_t)idx * 27;              // idx = co*384+ci
#pragma unroll
    for (int tap = 0; tap < 27; ++tap)
        Wb[(size_t)tap * (CDIM * CDIM) + idx] = f2bf(wp[tap]);
}
__device__ __forceinline__ void cvt_body(const float* __restrict__ src,
                                         ushort_t* __restrict__ dst, int i) {
    float4 v = ((const float4*)src)[i];
    uint2 o; o.x = pk2(v.x, v.y); o.y = pk2(v.z, v.w);
    ((uint2*)dst)[i] = o;
}
__global__ __launch_bounds__(256)
void prep_weights_kernel(const float* w1, const float* w2, const float* w3,
                         const float* w4, const float* ipw, const float* opw,
                         const float* xpw,
                         ushort_t* Wb1, ushort_t* Wb2, ushort_t* w3b, ushort_t* w4b,
                         ushort_t* ipwb, ushort_t* opwb, ushort_t* xpwb) {
    const int bid = blockIdx.x, t = threadIdx.x;
    if      (bid < 576)  wconv_body(w1, Wb1, bid * 256 + t);
    else if (bid < 1152) wconv_body(w2, Wb2, (bid - 576) * 256 + t);
    else if (bid < 1296) cvt_body(w3, w3b, (bid - 1152) * 256 + t);
    else if (bid < 1440) cvt_body(w4, w4b, (bid - 1296) * 256 + t);
    else if (bid < 2016) cvt_body(ipw, ipwb, (bid - 1440) * 256 + t);
    else if (bid < 2304) cvt_body(opw, opwb, (bid - 2016) * 256 + t);
    else                 cvt_body(xpw, xpwb, (bid - 2304) * 256 + t);
}

// ---------------------------------------------------------------------------
// Pad + transpose to channels-last bf16: src[b][c][16^3] -> Xp[b][18][18][18][384]
// ---------------------------------------------------------------------------
__global__ __launch_bounds__(384)
void pad_kernel(const float* __restrict__ src, ushort_t* __restrict__ Xp) {
    const int blk = blockIdx.x;                          // b(4) d(16) h(16)
    const int b = blk >> 8, d = (blk >> 4) & 15, h = blk & 15;
    const int ci = threadIdx.x;
    const float* sp = src + (size_t)(b * CDIM + ci) * SDIM + d * 256 + h * 16;
    ushort_t* dp = Xp + ((((size_t)(b * 18 + d + 1) * 18) + (h + 1)) * 18 + 1) * CDIM + ci;
#pragma unroll
    for (int w = 0; w < 16; ++w)
        dp[(size_t)w * CDIM] = f2bf(sp[w]);
}

// ---------------------------------------------------------------------------
// Fused: v = relu((P0+P1+P2+P3 - m)*r) -> pad/transpose channels-last bf16 Xp.
// Partials are bf16, contiguous at P + z*PSTRIDE.
// ---------------------------------------------------------------------------
__global__ __launch_bounds__(384)
void pad_fuse2_kernel(const ushort_t* __restrict__ P, const float* __restrict__ stats,
                      ushort_t* __restrict__ Xp) {
    const int blk = blockIdx.x;
    const int b = blk >> 8, d = (blk >> 4) & 15, h = blk & 15;
    const int ci = threadIdx.x;
    const size_t o = (size_t)(b * CDIM + ci) * SDIM + d * 256 + h * 16;
    const float m = stats[(b * CDIM + ci) * 2], r = stats[(b * CDIM + ci) * 2 + 1];
    union { uint4 q[2]; ushort_t u[16]; } p[4];
#pragma unroll
    for (int z = 0; z < 4; ++z) {
        p[z].q[0] = ((const uint4*)(P + (size_t)z * PSTRIDE + o))[0];
        p[z].q[1] = ((const uint4*)(P + (size_t)z * PSTRIDE + o))[1];
    }
    ushort_t* dp = Xp + ((((size_t)(b * 18 + d + 1) * 18) + (h + 1)) * 18 + 1) * CDIM + ci;
#pragma unroll
    for (int w = 0; w < 16; ++w) {
        const float v = bf2f(p[0].u[w]) + bf2f(p[1].u[w]) + bf2f(p[2].u[w]) + bf2f(p[3].u[w]);
        dp[(size_t)w * CDIM] = f2bf(fmaxf((v - m) * r, 0.f));
    }
}

// ---------------------------------------------------------------------------
// Fused: S = relu((sumP-m2)*r2) + relu((C3-m3)*r3) -> pad channels-last bf16.
// ---------------------------------------------------------------------------
__global__ __launch_bounds__(384)
void pad_fuse3_kernel(const ushort_t* __restrict__ P, const float* __restrict__ st2,
                      const ushort_t* __restrict__ C3, const float* __restrict__ st3,
                      ushort_t* __restrict__ Xp) {
    const int blk = blockIdx.x;
    const int b = blk >> 8, d = (blk >> 4) & 15, h = blk & 15;
    const int ci = threadIdx.x;
    const size_t o = (size_t)(b * CDIM + ci) * SDIM + d * 256 + h * 16;
    const float m2 = st2[(b * CDIM + ci) * 2], r2 = st2[(b * CDIM + ci) * 2 + 1];
    const float m3 = st3[(b * CDIM + ci) * 2], r3 = st3[(b * CDIM + ci) * 2 + 1];
    union { uint4 q[2]; ushort_t u[16]; } p[4], e;
#pragma unroll
    for (int z = 0; z < 4; ++z) {
        p[z].q[0] = ((const uint4*)(P + (size_t)z * PSTRIDE + o))[0];
        p[z].q[1] = ((const uint4*)(P + (size_t)z * PSTRIDE + o))[1];
    }
    e.q[0] = ((const uint4*)(C3 + o))[0]; e.q[1] = ((const uint4*)(C3 + o))[1];
    ushort_t* dp = Xp + ((((size_t)(b * 18 + d + 1) * 18) + (h + 1)) * 18 + 1) * CDIM + ci;
#pragma unroll
    for (int w = 0; w < 16; ++w) {
        const float sum = bf2f(p[0].u[w]) + bf2f(p[1].u[w]) + bf2f(p[2].u[w]) + bf2f(p[3].u[w]);
        const float x1 = fmaxf((sum - m2) * r2, 0.f);
        const float x2 = fmaxf((bf2f(e.u[w]) - m3) * r3, 0.f);
        dp[(size_t)w * CDIM] = f2bf(x1 + x2);
    }
}

// ---------------------------------------------------------------------------
// Implicit-GEMM conv via MFMA bf16: 512 threads (8 waves, 2co x 4sp),
// block 128co x 256sp (full d-plane), gl_lds staging, XOR-swizzled content.
// MODE 0: 3x3x3 with z=4 tap-split (taps 7z..7z+6, last 6) -> P + z*PSTRIDE;
//         grid 64nt x 3co x 4z = 768 = exactly 3 blocks/CU (uniform load).
// MODE 2: 1x1x1 (center tap) -> Y; grid 192.
// ---------------------------------------------------------------------------
template<int MODE>
__global__ __launch_bounds__(512)
void conv_kernel(const ushort_t* __restrict__ Xp, const ushort_t* __restrict__ Wsrc,
                 ushort_t* __restrict__ Ybase) {
    const int wid = blockIdx.x;
    const int ntid = wid & 63;                           // (b,d) innermost
    const int rest = wid >> 6;
    const int co0 = (rest % 3) * 128;
    const int zz  = rest / 3;                            // 0..3 (MODE 0) / 0 (MODE 2)
    const int b  = ntid >> 4;
    const int d  = ntid & 15;
    const int t = threadIdx.x;
    const int lane = t & 63;
    const int wv = t >> 6;                               // 0..7
    const int wy = wv >> 2, wx = wv & 3;                 // co-half / sp-quarter

    int tap0, iters, kd0, kh0, kw0; ushort_t* Y;
    if (MODE == 2) {
        tap0 = 0; iters = 12; kd0 = 1; kh0 = 1; kw0 = 1; Y = Ybase;
    } else {
        tap0 = 7 * zz; iters = (zz == 3 ? 6 : 7) * 12;
        kd0 = tap0 / 9; const int r9 = tap0 - kd0 * 9;
        kh0 = r9 / 3; kw0 = r9 - kh0 * 3;
        Y = Ybase + (size_t)zz * PSTRIDE;
    }

    __shared__ __align__(16) ushort_t As[4096];          // [128][32] bf16, 8KB
    __shared__ __align__(16) ushort_t Bs[8192];          // [256][32] bf16, 16KB

    f32x4 acc[4][4];
#pragma unroll
    for (int i = 0; i < 4; ++i)
#pragma unroll
        for (int j = 0; j < 4; ++j) acc[i][j] = (f32x4){0.f, 0.f, 0.f, 0.f};

    // staging thread-constants (per-lane, fixed): swizzled source granule
    const int l4 = lane >> 2;
    const int cg = (((lane & 3) ^ ((lane >> 3) & 3)) << 3);
    const int rA = wv * 16 + l4;                         // A row (1 instr/wave)
    const int aTC = (co0 + rA) * CDIM + cg;
    int bTC[2];
#pragma unroll
    for (int i = 0; i < 2; ++i) {
        const int r = wv * 32 + i * 16 + l4;             // B row (2 instr/wave)
        bTC[i] = ((r >> 4) * 18 + (r & 15)) * CDIM + cg;
    }
    ushort_t* lA = &As[wv * 512];
    ushort_t* lB[2] = { &Bs[wv * 1024], &Bs[wv * 1024 + 512] };

    // uniform walking offsets
    int aoff = tap0 * (CDIM * CDIM);
    int goff = (((b * 18 + d + kd0) * 18 + kh0) * 18 + kw0) * CDIM;
    int c12 = 0, ckw = kw0, ckh = kh0;

    // fragment read bases (same XOR involution as writes)
    const int lm = lane & 15;
    const int sw8 = (((lane >> 4) ^ ((lm >> 1) & 3)) << 3);
    const int rA0 = (wy * 64 + lm) * 32 + sw8;           // + mi*512
    const int rB0 = (wx * 64 + lm) * 32 + sw8;           // + ni*512

    for (int idx = 0; idx < iters; ++idx) {
        gl16(Wsrc + aoff + aTC, lA);
        gl16(Xp + goff + bTC[0], lB[0]);
        gl16(Xp + goff + bTC[1], lB[1]);
        aoff += 32; goff += 32;
        if (++c12 == 12) {                               // tap wrap
            c12 = 0;
            aoff += CDIM * CDIM - CDIM;
            if (++ckw == 3) {
                ckw = 0;
                if (++ckh == 3) { ckh = 0; goff += 109440; }
                else goff += 5760;
            }
        }
        __syncthreads();                                 // drains vmcnt: LDS ready
        bf16x8 af[4], bfr[4];
#pragma unroll
        for (int mi = 0; mi < 4; ++mi)
            af[mi] = *reinterpret_cast<const bf16x8*>(&As[rA0 + mi * 512]);
#pragma unroll
        for (int ni = 0; ni < 4; ++ni)
            bfr[ni] = *reinterpret_cast<const bf16x8*>(&Bs[rB0 + ni * 512]);
#pragma unroll
        for (int mi = 0; mi < 4; ++mi)
#pragma unroll
            for (int ni = 0; ni < 4; ++ni)
                acc[mi][ni] = __builtin_amdgcn_mfma_f32_16x16x32_bf16(
                    af[mi], bfr[ni], acc[mi][ni], 0, 0, 0);
        __syncthreads();                                 // reads done before overwrite
    }

    // epilogue: C/D layout col(lane&15)=sp, row=(lane>>4)*4+j=co; bf16 store
    const int coB = co0 + wy * 64 + (lane >> 4) * 4;
#pragma unroll
    for (int mi = 0; mi < 4; ++mi) {
#pragma unroll
        for (int ni = 0; ni < 4; ++ni) {
            const int nl = wx * 64 + ni * 16 + lm;       // sp within plane
            const int s = d * 256 + nl;
            ushort_t* yp = Y + ((size_t)b * CDIM + (coB + mi * 16)) * SDIM + s;
#pragma unroll
            for (int j = 0; j < 4; ++j)
                yp[(size_t)j * SDIM] = f2bf(acc[mi][ni][j]);
        }
    }
}

// ---------------------------------------------------------------------------
// bf16 MFMA GEMM NT with gl_lds + 2-phase prefetch (round-11, unchanged).
// C[M,N] = A[M,K] x B[N,K]^T. N masked via address clamp + store mask.
// EPI 0: fp32 store (ldc); 1: xz split -> bf16 C/C2 (N=1536);
// 2: transposed fp32 float4 store C[b][n][l].
// ---------------------------------------------------------------------------
template<int EPI>
__global__ __launch_bounds__(256)
void gemm_gl_kernel(const ushort_t* __restrict__ A, const ushort_t* __restrict__ Bw,
                    void* __restrict__ Cv, void* __restrict__ C2v,
                    int M, int N, int K, int ldc, int nx) {
    const int wid = blockIdx.x;
    const int n0 = (wid % nx) * 128;
    const int m0 = (wid / nx) * 128;
    const int t = threadIdx.x;
    const int lane = t & 63;
    const int wv = t >> 6;
    const int wy = wv >> 1, wx = wv & 1;

    __shared__ __align__(16) ushort_t As[2][4096];
    __shared__ __align__(16) ushort_t Bs[2][4096];

    f32x4 acc[4][4];
#pragma unroll
    for (int i = 0; i < 4; ++i)
#pragma unroll
        for (int j = 0; j < 4; ++j) acc[i][j] = (f32x4){0.f, 0.f, 0.f, 0.f};

    const int l4 = lane >> 2;
    const int cg = (((lane & 3) ^ ((lane >> 3) & 3)) << 3);
    size_t aTC[2], bTC[2];
#pragma unroll
    for (int i = 0; i < 2; ++i) {
        const int r = wv * 32 + i * 16 + l4;
        aTC[i] = (size_t)(m0 + r) * K + cg;
        int br = n0 + r; if (br >= N) br = N - 1;        // clamp (masked at store)
        bTC[i] = (size_t)br * K + cg;
    }

    const int lm = lane & 15;
    const int sw8 = (((lane >> 4) ^ ((lm >> 1) & 3)) << 3);
    const int rA0 = (wy * 64 + lm) * 32 + sw8;
    const int rB0 = (wx * 64 + lm) * 32 + sw8;

    auto stage = [&](int bf, int ko) {
        ushort_t* la = &As[bf][wv * 1024];
        ushort_t* lb = &Bs[bf][wv * 1024];
        gl16(A + aTC[0] + ko, la);
        gl16(A + aTC[1] + ko, la + 512);
        gl16(Bw + bTC[0] + ko, lb);
        gl16(Bw + bTC[1] + ko, lb + 512);
    };

    const int KI = K >> 5;
    stage(0, 0);
    __syncthreads();

    int buf = 0;
    for (int kk = 0; kk < KI; ++kk) {
        if (kk + 1 < KI) stage(buf ^ 1, (kk + 1) * 32);
        bf16x8 af[4], bfr[4];
#pragma unroll
        for (int mi = 0; mi < 4; ++mi)
            af[mi] = *reinterpret_cast<const bf16x8*>(&As[buf][rA0 + mi * 512]);
#pragma unroll
        for (int ni = 0; ni < 4; ++ni)
            bfr[ni] = *reinterpret_cast<const bf16x8*>(&Bs[buf][rB0 + ni * 512]);
#pragma unroll
        for (int mi = 0; mi < 4; ++mi)
#pragma unroll
            for (int ni = 0; ni < 4; ++ni)
                acc[mi][ni] = __builtin_amdgcn_mfma_f32_16x16x32_bf16(
                    af[mi], bfr[ni], acc[mi][ni], 0, 0, 0);
        __syncthreads();
        buf ^= 1;
    }

    const int mB = m0 + wy * 64 + (lane >> 4) * 4;
    const int nB = n0 + wx * 64 + lm;
#pragma unroll
    for (int mi = 0; mi < 4; ++mi) {
#pragma unroll
        for (int ni = 0; ni < 4; ++ni) {
            const int n = nB + ni * 16;
            if (EPI == 2) {                              // transposed float4
                const int mrow = mB + mi * 16;
                const int bb = mrow >> 12, l = mrow & 4095;
                float4 st = {acc[mi][ni][0], acc[mi][ni][1],
                             acc[mi][ni][2], acc[mi][ni][3]};
                *reinterpret_cast<float4*>(
                    (float*)Cv + ((size_t)(bb * CDIM + n)) * SDIM + l) = st;
            } else {
#pragma unroll
                for (int j = 0; j < 4; ++j) {
                    const int m = mB + mi * 16 + j;
                    const float v = acc[mi][ni][j];
                    if (EPI == 0) {
                        if (n < N) ((float*)Cv)[(size_t)m * ldc + n] = v;
                    } else {                             // xz split, bf16 out
                        if (n < DINC) ((ushort_t*)Cv)[(size_t)m * DINC + n] = f2bf(v);
                        else ((ushort_t*)C2v)[(size_t)m * DINC + (n - DINC)] = f2bf(v);
                    }
                }
            }
        }
    }
}

// ---------------------------------------------------------------------------
// Reduction helper for instance-norm stats.
// ---------------------------------------------------------------------------
__device__ __forceinline__ void stats_reduce(float s, float ss, float* out) {
#pragma unroll
    for (int off = 32; off > 0; off >>= 1) {
        s += __shfl_down(s, off);
        ss += __shfl_down(ss, off);
    }
    __shared__ float rs[4], rss[4];
    const int wid = threadIdx.x >> 6;
    if ((threadIdx.x & 63) == 0) { rs[wid] = s; rss[wid] = ss; }
    __syncthreads();
    if (threadIdx.x == 0) {
        float S = rs[0] + rs[1] + rs[2] + rs[3];
        float SS = rss[0] + rss[1] + rss[2] + rss[3];
        float m = S * (1.f / SDIM);
        float var = SS * (1.f / SDIM) - m * m;
        out[0] = m;
        out[1] = rsqrtf(var + 1e-5f);
    }
}

// ---------------------------------------------------------------------------
// Combo stats (bf16): bc<1536 -> stats of sum of 4 partials into SA;
// bc>=1536 -> stats of X3 into SB (only when grid > 1536).
// ---------------------------------------------------------------------------
__global__ __launch_bounds__(256)
void inorm_stats_combo_kernel(const ushort_t* __restrict__ P, float* __restrict__ SA,
                              const ushort_t* __restrict__ X3, float* __restrict__ SB) {
    const int bid = blockIdx.x;
    float s = 0.f, ss = 0.f;
    if (bid < 1536) {
        const size_t row = (size_t)bid * SDIM;
        for (int i = threadIdx.x * 8; i < SDIM; i += 2048) {
            union { uint4 q; ushort_t u[8]; } p[4];
#pragma unroll
            for (int z = 0; z < 4; ++z)
                p[z].q = *(const uint4*)(P + (size_t)z * PSTRIDE + row + i);
#pragma unroll
            for (int j = 0; j < 8; ++j) {
                const float v = bf2f(p[0].u[j]) + bf2f(p[1].u[j])
                              + bf2f(p[2].u[j]) + bf2f(p[3].u[j]);
                s += v; ss += v * v;
            }
        }
        stats_reduce(s, ss, SA + bid * 2);
    } else {
        const int bc = bid - 1536;
        const ushort_t* xp = X3 + (size_t)bc * SDIM;
        for (int i = threadIdx.x * 8; i < SDIM; i += 2048) {
            union { uint4 q; ushort_t u[8]; } a;
            a.q = *(const uint4*)(xp + i);
#pragma unroll
            for (int j = 0; j < 8; ++j) {
                const float v = bf2f(a.u[j]);
                s += v; ss += v * v;
            }
        }
        stats_reduce(s, ss, SB + bc * 2);
    }
}

// ---------------------------------------------------------------------------
// InstanceNorm stats, single bf16 input.
// ---------------------------------------------------------------------------
__global__ __launch_bounds__(256)
void inorm_stats_kernel(const ushort_t* __restrict__ X, float* __restrict__ stats) {
    const int bc = blockIdx.x;
    const ushort_t* xp = X + (size_t)bc * SDIM;
    float s = 0.f, ss = 0.f;
    for (int i = threadIdx.x * 8; i < SDIM; i += 2048) {
        union { uint4 q; ushort_t u[8]; } a;
        a.q = *(const uint4*)(xp + i);
#pragma unroll
        for (int j = 0; j < 8; ++j) {
            const float v = bf2f(a.u[j]);
            s += v; ss += v * v;
        }
    }
    stats_reduce(s, ss, stats + bc * 2);
}

// ---------------------------------------------------------------------------
// Fused LayerNorm, coalesced: wave handles 8 tokens, butterfly reduce,
// LDS-staged coalesced output.
// ---------------------------------------------------------------------------
__global__ __launch_bounds__(256)
void layernorm_kernel(const ushort_t* __restrict__ C4, const float* __restrict__ stats,
                      const float* __restrict__ X, const float* __restrict__ gam,
                      const float* __restrict__ bet, ushort_t* __restrict__ Tn) {
    const int blk = blockIdx.x;
    const int b = blk >> 7;
    const int tile0 = (blk & 127) * 32;
    const int wv = threadIdx.x >> 6;
    const int lane = threadIdx.x & 63;
    const int l0 = tile0 + wv * 8;

    __shared__ ushort_t tile[32 * 384];

    float v[6][8];
    float s[8], ss[8];
#pragma unroll
    for (int t = 0; t < 8; ++t) { s[t] = 0.f; ss[t] = 0.f; }
    float g[6], be[6];

#pragma unroll
    for (int i = 0; i < 6; ++i) {
        const int c = lane + i * 64;
        g[i] = gam[c]; be[i] = bet[c];
        const size_t base = (size_t)(b * CDIM + c) * SDIM + l0;
        union { uint4 q; ushort_t u[8]; } cv;
        cv.q = *(const uint4*)(C4 + base);
        const float4 x0 = *(const float4*)(X + base);
        const float4 x1 = *(const float4*)(X + base + 4);
        const float xs[8] = {x0.x, x0.y, x0.z, x0.w, x1.x, x1.y, x1.z, x1.w};
        const float m = stats[(b * CDIM + c) * 2];
        const float r = stats[(b * CDIM + c) * 2 + 1];
#pragma unroll
        for (int t = 0; t < 8; ++t) {
            const float val = fmaxf((bf2f(cv.u[t]) - m) * r, 0.f) + xs[t];
            v[i][t] = val;
            s[t] += val; ss[t] += val * val;
        }
    }
#pragma unroll
    for (int off = 32; off > 0; off >>= 1) {
#pragma unroll
        for (int t = 0; t < 8; ++t) {
            s[t] += __shfl_xor(s[t], off);
            ss[t] += __shfl_xor(ss[t], off);
        }
    }
#pragma unroll
    for (int t = 0; t < 8; ++t) {
        const float mean = s[t] * (1.f / CDIM);
        const float rstd = rsqrtf(ss[t] * (1.f / CDIM) - mean * mean + 1e-5f);
        const int trow = (wv * 8 + t) * 384;
#pragma unroll
        for (int i = 0; i < 6; ++i) {
            const int c = lane + i * 64;
            tile[trow + c] = f2bf((v[i][t] - mean) * rstd * g[i] + be[i]);
        }
    }
    __syncthreads();
    uint4* dst = (uint4*)(Tn + ((size_t)b * 4096 + tile0) * CDIM);
    const uint4* srcp = (const uint4*)tile;
#pragma unroll
    for (int k = 0; k < 6; ++k)
        dst[k * 256 + threadIdx.x] = srcp[k * 256 + threadIdx.x];
}

// ---------------------------------------------------------------------------
// Tiled fp32 GEMM for dt_proj (K=24), NT, bias+softplus, bf16 store.
// ---------------------------------------------------------------------------
__global__ __launch_bounds__(256)
void gemm_dtproj_kernel(const float* __restrict__ A, const float* __restrict__ B,
                        ushort_t* __restrict__ C, const float* __restrict__ bias,
                        int M, int N, int K, int lda, int ldb, int ldc) {
    __shared__ __align__(16) float As[16][132];
    __shared__ __align__(16) float Bs[16][68];
    const int t = threadIdx.x;
    const int m0 = blockIdx.y * 128;
    const int n0 = blockIdx.x * 64;

    float acc[8][4];
#pragma unroll
    for (int i = 0; i < 8; ++i)
#pragma unroll
        for (int j = 0; j < 4; ++j) acc[i][j] = 0.f;

    const int mr = (t & 15) * 8;
    const int nr = (t >> 4) * 4;

    for (int k0 = 0; k0 < K; k0 += 16) {
#pragma unroll
        for (int idx = 0; idx < 8; ++idx) {
            const int e = idx * 256 + t;
            const int k = e & 15, m = e >> 4;
            float v = 0.f;
            if (k0 + k < K) v = A[(size_t)(m0 + m) * lda + (k0 + k)];
            As[k][m] = v;
        }
#pragma unroll
        for (int idx = 0; idx < 4; ++idx) {
            const int e = idx * 256 + t;
            const int k = e & 15, n = e >> 4;
            float v = 0.f;
            if ((n0 + n) < N && (k0 + k) < K) v = B[(size_t)(n0 + n) * ldb + (k0 + k)];
            Bs[k][n] = v;
        }
        __syncthreads();
#pragma unroll
        for (int k = 0; k < 16; ++k) {
            float4 a0 = *(const float4*)&As[k][mr];
            float4 a1 = *(const float4*)&As[k][mr + 4];
            float4 b0 = *(const float4*)&Bs[k][nr];
            const float av[8] = {a0.x, a0.y, a0.z, a0.w, a1.x, a1.y, a1.z, a1.w};
            const float bv[4] = {b0.x, b0.y, b0.z, b0.w};
#pragma unroll
            for (int i = 0; i < 8; ++i)
#pragma unroll
                for (int j = 0; j < 4; ++j)
                    acc[i][j] = fmaf(av[i], bv[j], acc[i][j]);
        }
        __syncthreads();
    }

#pragma unroll
    for (int i = 0; i < 8; ++i) {
        const int m = m0 + mr + i;
#pragma unroll
        for (int j = 0; j < 4; ++j) {
            const int n = n0 + nr + j;
            if (n >= N) continue;
            float v = acc[i][j] + bias[n];
            v = (v > 20.f) ? v : log1pf(__expf(v));
            C[(size_t)m * ldc + n] = f2bf(v);
        }
    }
}

// ---------------------------------------------------------------------------
// Causal depthwise conv1d (K=4) + bias + SiLU, bf16 in/out. 4 tokens/thread.
// ---------------------------------------------------------------------------
__global__ __launch_bounds__(256)
void dwconv_silu_kernel(const ushort_t* __restrict__ Xin, const float* __restrict__ W,
                        const float* __restrict__ bias, ushort_t* __restrict__ U) {
    const int dch = blockIdx.x * 256 + threadIdx.x;
    const int l0 = blockIdx.y * 4, b = blockIdx.z;
    const float4 w4 = ((const float4*)W)[dch];
    const float wk[4] = {w4.x, w4.y, w4.z, w4.w};
    const float bs = bias[dch];
    const size_t base = ((size_t)b * 4096 + l0) * DINC + dch;
    float r[7];
#pragma unroll
    for (int k = 0; k < 7; ++k) {
        const int ll = l0 - 3 + k;
        r[k] = (ll >= 0) ? bf2f(Xin[base + (size_t)(k - 3) * DINC]) : 0.f;
    }
#pragma unroll
    for (int j = 0; j < 4; ++j) {
        float acc = bs;
#pragma unroll
        for (int k = 0; k < 4; ++k) acc = fmaf(r[j + k], wk[k], acc);
        U[base + (size_t)j * DINC] = f2bf(acc / (1.f + __expf(-acc)));
    }
}

// ---------------------------------------------------------------------------
// Chunked parallel selective scan (3 phases). dt/u/z/y bf16; B,C fp32.
// ---------------------------------------------------------------------------
__global__ __launch_bounds__(256)
void scan_phase1_kernel(const ushort_t* __restrict__ DT, const ushort_t* __restrict__ U,
                        const float* __restrict__ DBL, const float* __restrict__ A_log,
                        float* __restrict__ HOUT, float* __restrict__ SDT) {
    const int b = blockIdx.z, chunk = blockIdx.y;
    const int dch = blockIdx.x * 256 + threadIdx.x;
    float Arow[16];
#pragma unroll
    for (int n = 0; n < NST; ++n) Arow[n] = -__expf(A_log[dch * NST + n]);

    __shared__ float bcs[LCHUNK][16];
    const size_t tokbase = (size_t)b * 4096 + chunk * LCHUNK;
#pragma unroll
    for (int idx = 0; idx < 4; ++idx) {
        const int e = idx * 256 + threadIdx.x;
        bcs[e >> 4][e & 15] = DBL[(tokbase + (e >> 4)) * 56 + 24 + (e & 15)];
    }
    __syncthreads();

    size_t off = tokbase * DINC + dch;
    float h[16];
#pragma unroll
    for (int n = 0; n < NST; ++n) h[n] = 0.f;
    float sdt = 0.f;
    float cdt = bf2f(DT[off]), cu = bf2f(U[off]);
    for (int t = 0; t < LCHUNK; ++t) {
        float ndt = 0.f, nu = 0.f;
        if (t < LCHUNK - 1) { ndt = bf2f(DT[off + DINC]); nu = bf2f(U[off + DINC]); }
        sdt += cdt;
        const float du = cdt * cu;
#pragma unroll
        for (int n = 0; n < NST; ++n)
            h[n] = __expf(cdt * Arow[n]) * h[n] + du * bcs[t][n];
        off += DINC;
        cdt = ndt; cu = nu;
    }
    float* hp = HOUT + (((size_t)(b * DINC + dch) * NCHUNK + chunk) << 4);
#pragma unroll
    for (int n = 0; n < NST; ++n) hp[n] = h[n];
    SDT[(size_t)(b * DINC + dch) * NCHUNK + chunk] = sdt;
}

__global__ __launch_bounds__(256)
void scan_phase2_kernel(float* __restrict__ HOUT, const float* __restrict__ SDT,
                        const float* __restrict__ A_log) {
    const int t = blockIdx.x * 256 + threadIdx.x;        // 49152
    const int b = t / (DINC * NST);
    const int rem = t - b * (DINC * NST);
    const int d = rem >> 4, n = rem & 15;
    const float An = -__expf(A_log[d * NST + n]);
    float* hp = HOUT + (((size_t)(b * DINC + d) * NCHUNK) << 4) + n;
    const float* sp = SDT + (size_t)(b * DINC + d) * NCHUNK;
    float H = 0.f;
    for (int c = 0; c < NCHUNK; ++c) {
        const float tmp = hp[c * 16];
        const float dA = __expf(An * sp[c]);
        hp[c * 16] = H;
        H = dA * H + tmp;
    }
}

__global__ __launch_bounds__(256)
void scan_phase3_kernel(ushort_t* __restrict__ DT, const ushort_t* __restrict__ U,
                        const float* __restrict__ DBL, const ushort_t* __restrict__ Z,
                        const float* __restrict__ A_log, const float* __restrict__ D_skip,
                        const float* __restrict__ HOUT) {
    const int b = blockIdx.z, chunk = blockIdx.y;
    const int dch = blockIdx.x * 256 + threadIdx.x;
    float Arow[16];
#pragma unroll
    for (int n = 0; n < NST; ++n) Arow[n] = -__expf(A_log[dch * NST + n]);
    const float Dsk = D_skip[dch];

    __shared__ float bcs[LCHUNK][32];
    const size_t tokbase = (size_t)b * 4096 + chunk * LCHUNK;
#pragma unroll
    for (int idx = 0; idx < 8; ++idx) {
        const int e = idx * 256 + threadIdx.x;
        bcs[e >> 5][e & 31] = DBL[(tokbase + (e >> 5)) * 56 + 24 + (e & 31)];
    }
    __syncthreads();

    float h[16];
    const float* hp = HOUT + (((size_t)(b * DINC + dch) * NCHUNK + chunk) << 4);
#pragma unroll
    for (int n = 0; n < NST; ++n) h[n] = hp[n];

    size_t off = tokbase * DINC + dch;
    float cdt = bf2f(DT[off]), cu = bf2f(U[off]), cz = bf2f(Z[off]);
    for (int t = 0; t < LCHUNK; ++t) {
        float ndt = 0.f, nu = 0.f, nz = 0.f;
        if (t < LCHUNK - 1) {
            ndt = bf2f(DT[off + DINC]); nu = bf2f(U[off + DINC]); nz = bf2f(Z[off + DINC]);
        }
        const float du = cdt * cu;
        float y = 0.f;
#pragma unroll
        for (int n = 0; n < NST; ++n) {
            h[n] = __expf(cdt * Arow[n]) * h[n] + du * bcs[t][n];
            y = fmaf(h[n], bcs[t][16 + n], y);
        }
        y += cu * Dsk;
        const float sz = cz / (1.f + __expf(-cz));
        DT[off] = f2bf(y * sz);
        off += DINC;
        cdt = ndt; cu = nu; cz = nz;
    }
}

// ---------------------------------------------------------------------------
extern "C" void kernel_launch(void* const* d_in, const int* in_sizes, int n_in,
                              void* d_out, int out_size, void* d_ws, size_t ws_size,
                              hipStream_t stream) {
    (void)in_sizes; (void)n_in; (void)out_size; (void)ws_size;
    const float* x         = (const float*)d_in[0];
    const float* w1        = (const float*)d_in[1];
    const float* w2        = (const float*)d_in[3];
    const float* w3        = (const float*)d_in[5];
    const float* w4        = (const float*)d_in[7];
    const float* ln_g      = (const float*)d_in[9];
    const float* ln_b      = (const float*)d_in[10];
    const float* in_proj_w = (const float*)d_in[11];
    const float* conv1d_w  = (const float*)d_in[12];
    const float* conv1d_b  = (const float*)d_in[13];
    const float* x_proj_w  = (const float*)d_in[14];
    const float* dt_proj_w = (const float*)d_in[15];
    const float* dt_proj_b = (const float*)d_in[16];
    const float* A_log     = (const float*)d_in[17];
    const float* D_skip    = (const float*)d_in[18];
    const float* out_proj_w= (const float*)d_in[19];
    float* out = (float*)d_out;

    // Workspace regions (floats): R0..R4. Lifetimes disjoint where aliased.
    float* ws = (float*)d_ws;
    float* R0 = ws;                    //  6291456
    float* R1 = ws + 6291456;          //  6291456
    float* R2 = ws + 12582912;         // 12582912
    float* R3 = ws + 25165824;         // 12582912
    float* R4 = ws + 37748736;         // 12582912

    // GSC-phase aliases: 4 bf16 partials contiguous across R0+R1
    ushort_t* P     = (ushort_t*)R0;                 // P+z*PSTRIDE, z=0..3 (50MB)
    ushort_t* C34   = (ushort_t*)R3;                 // c3/c4 outputs bf16
    ushort_t* Wb1   = (ushort_t*)R2;                 // 3981312 bf16
    ushort_t* Xp    = (ushort_t*)(R2 + 2097152);     // 8957952 bf16
    ushort_t* w3b   = (ushort_t*)(R2 + 6576128);     // 147456 bf16
    ushort_t* w4b   = (ushort_t*)(R2 + 6649856);     // 147456 bf16
    ushort_t* Wb2   = (ushort_t*)(R2 + 6723584);     // 3981312 bf16
    float*    SA    = R4;                            // stats A
    float*    SB    = R4 + 4096;                     // stats B
    ushort_t* ipwb  = (ushort_t*)(R4 + 6291456);
    ushort_t* opwb  = (ushort_t*)(R4 + 6586368);
    ushort_t* xpwb  = (ushort_t*)(R4 + 6733824);
    // Mamba-phase aliases
    ushort_t* tnb   = (ushort_t*)R0;                 // 16384*384 bf16
    float*    DBL   = R0 + 3145728;                  // 16384*56 fp32
    float*    HOUT  = R1;
    float*    SDT   = R1 + 3145728;
    ushort_t* XIN   = (ushort_t*)R2;
    ushort_t* Zb    = (ushort_t*)R3;
    ushort_t* Ub    = (ushort_t*)R4;
    ushort_t* DTb   = (ushort_t*)R2;

    const size_t XP_BYTES = (size_t)4 * 18 * 18 * 18 * CDIM * 2;

    // ---- upfront: zero pad borders, convert all weights, pad x ----
    hipMemsetAsync(Xp, 0, XP_BYTES, stream);
    prep_weights_kernel<<<2346, 256, 0, stream>>>(
        w1, w2, w3, w4, in_proj_w, out_proj_w, x_proj_w,
        Wb1, Wb2, w3b, w4b, ipwb, opwb, xpwb);
    pad_kernel<<<1024, 384, 0, stream>>>(x, Xp);
    // ---- c1 (3x3x3 z=4 -> 768 blocks = 3/CU exact) + c3 (1x1) ----
    conv_kernel<0><<<768, 512, 0, stream>>>(Xp, Wb1, P);
    conv_kernel<2><<<192, 512, 0, stream>>>(Xp, w3b, C34);
    inorm_stats_combo_kernel<<<3072, 256, 0, stream>>>(P, SA, C34, SB);
    pad_fuse2_kernel<<<1024, 384, 0, stream>>>(P, SA, Xp);                  // x1a
    // ---- c2 ----
    conv_kernel<0><<<768, 512, 0, stream>>>(Xp, Wb2, P);
    inorm_stats_combo_kernel<<<1536, 256, 0, stream>>>(P, SA, nullptr, nullptr);
    pad_fuse3_kernel<<<1024, 384, 0, stream>>>(P, SA, C34, SB, Xp);         // S
    // ---- c4 (1x1) ----
    conv_kernel<2><<<192, 512, 0, stream>>>(Xp, w4b, C34);
    inorm_stats_kernel<<<1536, 256, 0, stream>>>(C34, SA);
    // ---- fused relu(IN(c4)) + x residual + LayerNorm -> tn bf16 [b][l][c]
    layernorm_kernel<<<512, 256, 0, stream>>>(C34, SA, x, ln_g, ln_b, tnb);
    // ---- in_proj (bf16 MFMA, gl_lds+prefetch): tn x W^T -> XIN | Zb (bf16)
    gemm_gl_kernel<1><<<1536, 256, 0, stream>>>(
        tnb, ipwb, XIN, Zb, 16384, 1536, CDIM, 0, 12);
    // ---- causal depthwise conv + SiLU -> Ub (bf16)
    dwconv_silu_kernel<<<dim3(3, 1024, 4), 256, 0, stream>>>(XIN, conv1d_w, conv1d_b, Ub);
    // ---- x_proj (bf16 MFMA, N=56 masked): u x W^T -> DBL (fp32)
    gemm_gl_kernel<0><<<128, 256, 0, stream>>>(
        Ub, xpwb, DBL, nullptr, 16384, 56, DINC, 56, 1);
    // ---- dt_proj (fp32 VALU, K=24) + bias + softplus -> DTb (bf16)
    gemm_dtproj_kernel<<<dim3(12, 128), 256, 0, stream>>>(
        DBL, dt_proj_w, DTb, dt_proj_b, 16384, DINC, 24, 56, 24, DINC);
    // ---- chunked parallel selective scan (y bf16 over DTb)
    scan_phase1_kernel<<<dim3(3, NCHUNK, 4), 256, 0, stream>>>(
        DTb, Ub, DBL, A_log, HOUT, SDT);
    scan_phase2_kernel<<<192, 256, 0, stream>>>(HOUT, SDT, A_log);
    scan_phase3_kernel<<<dim3(3, NCHUNK, 4), 256, 0, stream>>>(
        DTb, Ub, DBL, Zb, A_log, D_skip, HOUT);
    // ---- out_proj (bf16 MFMA) -> d_out transposed fp32
    gemm_gl_kernel<2><<<384, 256, 0, stream>>>(
        DTb, opwb, out, nullptr, 16384, CDIM, DINC, 0, 3);
}

// Round 14
// 737.072 us; speedup vs baseline: 1.1218x; 1.1218x over previous
//
#include <hip/hip_runtime.h>
#include <math.h>

#define CDIM 384
#define SDIM 4096
#define BDIM 4
#define DINC 768
#define NST  16
#define NCHUNK 64
#define LCHUNK 64
#define PSTRIDE 6291456   // ELEMENTS per conv partial [B,C,S] (bf16)

typedef unsigned short ushort_t;
typedef unsigned int uint_t;
typedef __attribute__((ext_vector_type(4))) float f32x4;
typedef __attribute__((ext_vector_type(8))) short bf16x8;

__device__ __forceinline__ ushort_t f2bf(float f) {
    union { float f; uint_t u; } v; v.f = f;
    uint_t r = v.u + 0x7FFFu + ((v.u >> 16) & 1u);   // round-to-nearest-even
    return (ushort_t)(r >> 16);
}
__device__ __forceinline__ float bf2f(ushort_t u) {
    union { uint_t i; float f; } v; v.i = ((uint_t)u) << 16; return v.f;
}
__device__ __forceinline__ uint_t pk2(float a, float b) {
    return (uint_t)f2bf(a) | ((uint_t)f2bf(b) << 16);
}
// async global->LDS, 16B per lane, dest = wave-uniform base + lane*16
__device__ __forceinline__ void gl16(const ushort_t* g, ushort_t* l) {
    __builtin_amdgcn_global_load_lds(
        (const __attribute__((address_space(1))) void*)(g),
        (__attribute__((address_space(3))) void*)(l), 16, 0, 0);
}

// ---------------------------------------------------------------------------
// Merged weight prep: all fp32->bf16 weight conversions in one dispatch.
// ---------------------------------------------------------------------------
__device__ __forceinline__ void wconv_body(const float* __restrict__ W,
                                           ushort_t* __restrict__ Wb, int idx) {
    const float* wp = W + (size_t)idx * 27;              // idx = co*384+ci
#pragma unroll
    for (int tap = 0; tap < 27; ++tap)
        Wb[(size_t)tap * (CDIM * CDIM) + idx] = f2bf(wp[tap]);
}
__device__ __forceinline__ void cvt_body(const float* __restrict__ src,
                                         ushort_t* __restrict__ dst, int i) {
    float4 v = ((const float4*)src)[i];
    uint2 o; o.x = pk2(v.x, v.y); o.y = pk2(v.z, v.w);
    ((uint2*)dst)[i] = o;
}
__global__ __launch_bounds__(256)
void prep_weights_kernel(const float* w1, const float* w2, const float* w3,
                         const float* w4, const float* ipw, const float* opw,
                         const float* xpw,
                         ushort_t* Wb1, ushort_t* Wb2, ushort_t* w3b, ushort_t* w4b,
                         ushort_t* ipwb, ushort_t* opwb, ushort_t* xpwb) {
    const int bid = blockIdx.x, t = threadIdx.x;
    if      (bid < 576)  wconv_body(w1, Wb1, bid * 256 + t);
    else if (bid < 1152) wconv_body(w2, Wb2, (bid - 576) * 256 + t);
    else if (bid < 1296) cvt_body(w3, w3b, (bid - 1152) * 256 + t);
    else if (bid < 1440) cvt_body(w4, w4b, (bid - 1296) * 256 + t);
    else if (bid < 2016) cvt_body(ipw, ipwb, (bid - 1440) * 256 + t);
    else if (bid < 2304) cvt_body(opw, opwb, (bid - 2016) * 256 + t);
    else                 cvt_body(xpw, xpwb, (bid - 2304) * 256 + t);
}

// ---------------------------------------------------------------------------
// Pad + transpose to channels-last bf16: src[b][c][16^3] -> Xp[b][18][18][18][384]
// ---------------------------------------------------------------------------
__global__ __launch_bounds__(384)
void pad_kernel(const float* __restrict__ src, ushort_t* __restrict__ Xp) {
    const int blk = blockIdx.x;                          // b(4) d(16) h(16)
    const int b = blk >> 8, d = (blk >> 4) & 15, h = blk & 15;
    const int ci = threadIdx.x;
    const float* sp = src + (size_t)(b * CDIM + ci) * SDIM + d * 256 + h * 16;
    ushort_t* dp = Xp + ((((size_t)(b * 18 + d + 1) * 18) + (h + 1)) * 18 + 1) * CDIM + ci;
#pragma unroll
    for (int w = 0; w < 16; ++w)
        dp[(size_t)w * CDIM] = f2bf(sp[w]);
}

// ---------------------------------------------------------------------------
// Fused: v = relu((P0+P1 - m)*r) -> pad/transpose channels-last bf16 Xp.
// ---------------------------------------------------------------------------
__global__ __launch_bounds__(384)
void pad_fuse2_kernel(const ushort_t* __restrict__ P0, const ushort_t* __restrict__ P1,
                      const float* __restrict__ stats, ushort_t* __restrict__ Xp) {
    const int blk = blockIdx.x;
    const int b = blk >> 8, d = (blk >> 4) & 15, h = blk & 15;
    const int ci = threadIdx.x;
    const size_t o = (size_t)(b * CDIM + ci) * SDIM + d * 256 + h * 16;
    const float m = stats[(b * CDIM + ci) * 2], r = stats[(b * CDIM + ci) * 2 + 1];
    union { uint4 q[2]; ushort_t u[16]; } a, c;
    a.q[0] = ((const uint4*)(P0 + o))[0]; a.q[1] = ((const uint4*)(P0 + o))[1];
    c.q[0] = ((const uint4*)(P1 + o))[0]; c.q[1] = ((const uint4*)(P1 + o))[1];
    ushort_t* dp = Xp + ((((size_t)(b * 18 + d + 1) * 18) + (h + 1)) * 18 + 1) * CDIM + ci;
#pragma unroll
    for (int w = 0; w < 16; ++w) {
        const float v = bf2f(a.u[w]) + bf2f(c.u[w]);
        dp[(size_t)w * CDIM] = f2bf(fmaxf((v - m) * r, 0.f));
    }
}

// ---------------------------------------------------------------------------
// Fused: S = relu((P0+P1-m2)*r2) + relu((C3-m3)*r3) -> pad channels-last bf16.
// ---------------------------------------------------------------------------
__global__ __launch_bounds__(384)
void pad_fuse3_kernel(const ushort_t* __restrict__ P0, const ushort_t* __restrict__ P1,
                      const float* __restrict__ st2, const ushort_t* __restrict__ C3,
                      const float* __restrict__ st3, ushort_t* __restrict__ Xp) {
    const int blk = blockIdx.x;
    const int b = blk >> 8, d = (blk >> 4) & 15, h = blk & 15;
    const int ci = threadIdx.x;
    const size_t o = (size_t)(b * CDIM + ci) * SDIM + d * 256 + h * 16;
    const float m2 = st2[(b * CDIM + ci) * 2], r2 = st2[(b * CDIM + ci) * 2 + 1];
    const float m3 = st3[(b * CDIM + ci) * 2], r3 = st3[(b * CDIM + ci) * 2 + 1];
    union { uint4 q[2]; ushort_t u[16]; } a, c, e;
    a.q[0] = ((const uint4*)(P0 + o))[0]; a.q[1] = ((const uint4*)(P0 + o))[1];
    c.q[0] = ((const uint4*)(P1 + o))[0]; c.q[1] = ((const uint4*)(P1 + o))[1];
    e.q[0] = ((const uint4*)(C3 + o))[0]; e.q[1] = ((const uint4*)(C3 + o))[1];
    ushort_t* dp = Xp + ((((size_t)(b * 18 + d + 1) * 18) + (h + 1)) * 18 + 1) * CDIM + ci;
#pragma unroll
    for (int w = 0; w < 16; ++w) {
        const float x1 = fmaxf((bf2f(a.u[w]) + bf2f(c.u[w]) - m2) * r2, 0.f);
        const float x2 = fmaxf((bf2f(e.u[w]) - m3) * r3, 0.f);
        dp[(size_t)w * CDIM] = f2bf(x1 + x2);
    }
}

// ---------------------------------------------------------------------------
// Implicit-GEMM conv via MFMA bf16: 512 threads (8 waves, 2co x 4sp),
// block 128co x 256sp (full d-plane). gl_lds staging, XOR-swizzled content.
// MODE 0: c2 (z in {0,1} tap-split -> Y01+z*PSTRIDE)
// MODE 1: c1 (z in {0,1}) + c3 1x1 fused as z==2 (W3 -> Y2)
// MODE 2: pure 1x1 (c4 -> Y2)
// ---------------------------------------------------------------------------
template<int MODE>
__global__ __launch_bounds__(512)
void conv_kernel(const ushort_t* __restrict__ Xp, const ushort_t* __restrict__ Wb,
                 const ushort_t* __restrict__ W3, ushort_t* __restrict__ Y01,
                 ushort_t* __restrict__ Y2) {
    const int wid = blockIdx.x;
    const int ntid = wid & 63;                           // (b,d) innermost
    const int rest = wid >> 6;
    const int co0 = (rest % 3) * 128;
    const int zz  = rest / 3;
    const int b  = ntid >> 4;
    const int d  = ntid & 15;
    const int t = threadIdx.x;
    const int lane = t & 63;
    const int wv = t >> 6;                               // 0..7
    const int wy = wv >> 2, wx = wv & 3;                 // co-half / sp-quarter

    const bool is1x1 = (MODE == 2) || (MODE == 1 && zz == 2);
    const ushort_t* Wsrc; int tap0, iters, kd0, kh0, kw0; ushort_t* Y;
    if (is1x1) {
        Wsrc = W3; tap0 = 0; iters = 12; kd0 = 1; kh0 = 1; kw0 = 1; Y = Y2;
    } else {
        Wsrc = Wb; tap0 = zz ? 14 : 0; iters = (zz ? 13 : 14) * 12;
        kd0 = zz ? 1 : 0; kh0 = zz ? 1 : 0; kw0 = zz ? 2 : 0;
        Y = Y01 + (size_t)zz * PSTRIDE;
    }

    __shared__ __align__(16) ushort_t As[4096];          // [128][32] bf16, 8KB
    __shared__ __align__(16) ushort_t Bs[8192];          // [256][32] bf16, 16KB

    f32x4 acc[4][4];
#pragma unroll
    for (int i = 0; i < 4; ++i)
#pragma unroll
        for (int j = 0; j < 4; ++j) acc[i][j] = (f32x4){0.f, 0.f, 0.f, 0.f};

    // staging thread-constants (per-lane, fixed): swizzled source granule
    const int l4 = lane >> 2;
    const int cg = (((lane & 3) ^ ((lane >> 3) & 3)) << 3);
    const int rA = wv * 16 + l4;                         // A row (1 instr/wave)
    const int aTC = (co0 + rA) * CDIM + cg;
    int bTC[2];
#pragma unroll
    for (int i = 0; i < 2; ++i) {
        const int r = wv * 32 + i * 16 + l4;             // B row (2 instr/wave)
        bTC[i] = ((r >> 4) * 18 + (r & 15)) * CDIM + cg;
    }
    ushort_t* lA = &As[wv * 512];
    ushort_t* lB[2] = { &Bs[wv * 1024], &Bs[wv * 1024 + 512] };

    // uniform walking offsets
    int aoff = tap0 * (CDIM * CDIM);
    int goff = (((b * 18 + d + kd0) * 18 + kh0) * 18 + kw0) * CDIM;
    int c12 = 0, ckw = kw0, ckh = kh0;

    // fragment read bases (same XOR involution as writes)
    const int lm = lane & 15;
    const int sw8 = (((lane >> 4) ^ ((lm >> 1) & 3)) << 3);
    const int rA0 = (wy * 64 + lm) * 32 + sw8;           // + mi*512
    const int rB0 = (wx * 64 + lm) * 32 + sw8;           // + ni*512

    for (int idx = 0; idx < iters; ++idx) {
        gl16(Wsrc + aoff + aTC, lA);
        gl16(Xp + goff + bTC[0], lB[0]);
        gl16(Xp + goff + bTC[1], lB[1]);
        aoff += 32; goff += 32;
        if (++c12 == 12) {                               // tap wrap
            c12 = 0;
            aoff += CDIM * CDIM - CDIM;
            if (++ckw == 3) {
                ckw = 0;
                if (++ckh == 3) { ckh = 0; goff += 109440; }
                else goff += 5760;
            }
        }
        __syncthreads();                                 // drains vmcnt: LDS ready
        bf16x8 af[4], bfr[4];
#pragma unroll
        for (int mi = 0; mi < 4; ++mi)
            af[mi] = *reinterpret_cast<const bf16x8*>(&As[rA0 + mi * 512]);
#pragma unroll
        for (int ni = 0; ni < 4; ++ni)
            bfr[ni] = *reinterpret_cast<const bf16x8*>(&Bs[rB0 + ni * 512]);
#pragma unroll
        for (int mi = 0; mi < 4; ++mi)
#pragma unroll
            for (int ni = 0; ni < 4; ++ni)
                acc[mi][ni] = __builtin_amdgcn_mfma_f32_16x16x32_bf16(
                    af[mi], bfr[ni], acc[mi][ni], 0, 0, 0);
        __syncthreads();                                 // reads done before overwrite
    }

    // epilogue: C/D layout col(lane&15)=sp, row=(lane>>4)*4+j=co; bf16 store
    const int coB = co0 + wy * 64 + (lane >> 4) * 4;
#pragma unroll
    for (int mi = 0; mi < 4; ++mi) {
#pragma unroll
        for (int ni = 0; ni < 4; ++ni) {
            const int nl = wx * 64 + ni * 16 + lm;       // sp within plane
            const int s = d * 256 + nl;
            ushort_t* yp = Y + ((size_t)b * CDIM + (coB + mi * 16)) * SDIM + s;
#pragma unroll
            for (int j = 0; j < 4; ++j)
                yp[(size_t)j * SDIM] = f2bf(acc[mi][ni][j]);
        }
    }
}

// ---------------------------------------------------------------------------
// bf16 MFMA GEMM NT with gl_lds + 2-phase prefetch.
// C[M,N] = A[M,K] x B[N,K]^T. N masked via address clamp + store mask.
// EPI 0: fp32 store (ldc); 1: xz split -> bf16 C/C2 (N=1536);
// 2: transposed fp32 float4 store C[b][n][l].
// ---------------------------------------------------------------------------
template<int EPI>
__global__ __launch_bounds__(256)
void gemm_gl_kernel(const ushort_t* __restrict__ A, const ushort_t* __restrict__ Bw,
                    void* __restrict__ Cv, void* __restrict__ C2v,
                    int M, int N, int K, int ldc, int nx) {
    const int wid = blockIdx.x;
    const int n0 = (wid % nx) * 128;
    const int m0 = (wid / nx) * 128;
    const int t = threadIdx.x;
    const int lane = t & 63;
    const int wv = t >> 6;
    const int wy = wv >> 1, wx = wv & 1;

    __shared__ __align__(16) ushort_t As[2][4096];
    __shared__ __align__(16) ushort_t Bs[2][4096];

    f32x4 acc[4][4];
#pragma unroll
    for (int i = 0; i < 4; ++i)
#pragma unroll
        for (int j = 0; j < 4; ++j) acc[i][j] = (f32x4){0.f, 0.f, 0.f, 0.f};

    const int l4 = lane >> 2;
    const int cg = (((lane & 3) ^ ((lane >> 3) & 3)) << 3);
    size_t aTC[2], bTC[2];
#pragma unroll
    for (int i = 0; i < 2; ++i) {
        const int r = wv * 32 + i * 16 + l4;
        aTC[i] = (size_t)(m0 + r) * K + cg;
        int br = n0 + r; if (br >= N) br = N - 1;        // clamp (masked at store)
        bTC[i] = (size_t)br * K + cg;
    }

    const int lm = lane & 15;
    const int sw8 = (((lane >> 4) ^ ((lm >> 1) & 3)) << 3);
    const int rA0 = (wy * 64 + lm) * 32 + sw8;
    const int rB0 = (wx * 64 + lm) * 32 + sw8;

    auto stage = [&](int bf, int ko) {
        ushort_t* la = &As[bf][wv * 1024];
        ushort_t* lb = &Bs[bf][wv * 1024];
        gl16(A + aTC[0] + ko, la);
        gl16(A + aTC[1] + ko, la + 512);
        gl16(Bw + bTC[0] + ko, lb);
        gl16(Bw + bTC[1] + ko, lb + 512);
    };

    const int KI = K >> 5;
    stage(0, 0);
    __syncthreads();

    int buf = 0;
    for (int kk = 0; kk < KI; ++kk) {
        if (kk + 1 < KI) stage(buf ^ 1, (kk + 1) * 32);
        bf16x8 af[4], bfr[4];
#pragma unroll
        for (int mi = 0; mi < 4; ++mi)
            af[mi] = *reinterpret_cast<const bf16x8*>(&As[buf][rA0 + mi * 512]);
#pragma unroll
        for (int ni = 0; ni < 4; ++ni)
            bfr[ni] = *reinterpret_cast<const bf16x8*>(&Bs[buf][rB0 + ni * 512]);
#pragma unroll
        for (int mi = 0; mi < 4; ++mi)
#pragma unroll
            for (int ni = 0; ni < 4; ++ni)
                acc[mi][ni] = __builtin_amdgcn_mfma_f32_16x16x32_bf16(
                    af[mi], bfr[ni], acc[mi][ni], 0, 0, 0);
        __syncthreads();
        buf ^= 1;
    }

    const int mB = m0 + wy * 64 + (lane >> 4) * 4;
    const int nB = n0 + wx * 64 + lm;
#pragma unroll
    for (int mi = 0; mi < 4; ++mi) {
#pragma unroll
        for (int ni = 0; ni < 4; ++ni) {
            const int n = nB + ni * 16;
            if (EPI == 2) {                              // transposed float4
                const int mrow = mB + mi * 16;
                const int bb = mrow >> 12, l = mrow & 4095;
                float4 st = {acc[mi][ni][0], acc[mi][ni][1],
                             acc[mi][ni][2], acc[mi][ni][3]};
                *reinterpret_cast<float4*>(
                    (float*)Cv + ((size_t)(bb * CDIM + n)) * SDIM + l) = st;
            } else {
#pragma unroll
                for (int j = 0; j < 4; ++j) {
                    const int m = mB + mi * 16 + j;
                    const float v = acc[mi][ni][j];
                    if (EPI == 0) {
                        if (n < N) ((float*)Cv)[(size_t)m * ldc + n] = v;
                    } else {                             // xz split, bf16 out
                        if (n < DINC) ((ushort_t*)Cv)[(size_t)m * DINC + n] = f2bf(v);
                        else ((ushort_t*)C2v)[(size_t)m * DINC + (n - DINC)] = f2bf(v);
                    }
                }
            }
        }
    }
}

// ---------------------------------------------------------------------------
// Reduction helper for instance-norm stats.
// ---------------------------------------------------------------------------
__device__ __forceinline__ void stats_reduce(float s, float ss, float* out) {
#pragma unroll
    for (int off = 32; off > 0; off >>= 1) {
        s += __shfl_down(s, off);
        ss += __shfl_down(ss, off);
    }
    __shared__ float rs[4], rss[4];
    const int wid = threadIdx.x >> 6;
    if ((threadIdx.x & 63) == 0) { rs[wid] = s; rss[wid] = ss; }
    __syncthreads();
    if (threadIdx.x == 0) {
        float S = rs[0] + rs[1] + rs[2] + rs[3];
        float SS = rss[0] + rss[1] + rss[2] + rss[3];
        float m = S * (1.f / SDIM);
        float var = SS * (1.f / SDIM) - m * m;
        out[0] = m;
        out[1] = rsqrtf(var + 1e-5f);
    }
}

// ---------------------------------------------------------------------------
// Combo stats (bf16 inputs): bc<1536 -> stats of (P0+P1) into SA;
// bc>=1536 -> stats of X3 into SB (only when grid > 1536).
// ---------------------------------------------------------------------------
__global__ __launch_bounds__(256)
void inorm_stats_combo_kernel(const ushort_t* __restrict__ P0,
                              const ushort_t* __restrict__ P1,
                              float* __restrict__ SA,
                              const ushort_t* __restrict__ X3,
                              float* __restrict__ SB) {
    const int bid = blockIdx.x;
    float s = 0.f, ss = 0.f;
    if (bid < 1536) {
        const ushort_t* p0 = P0 + (size_t)bid * SDIM;
        const ushort_t* p1 = P1 + (size_t)bid * SDIM;
        for (int i = threadIdx.x * 8; i < SDIM; i += 2048) {
            union { uint4 q; ushort_t u[8]; } a, c;
            a.q = *(const uint4*)(p0 + i);
            c.q = *(const uint4*)(p1 + i);
#pragma unroll
            for (int j = 0; j < 8; ++j) {
                const float v = bf2f(a.u[j]) + bf2f(c.u[j]);
                s += v; ss += v * v;
            }
        }
        stats_reduce(s, ss, SA + bid * 2);
    } else {
        const int bc = bid - 1536;
        const ushort_t* xp = X3 + (size_t)bc * SDIM;
        for (int i = threadIdx.x * 8; i < SDIM; i += 2048) {
            union { uint4 q; ushort_t u[8]; } a;
            a.q = *(const uint4*)(xp + i);
#pragma unroll
            for (int j = 0; j < 8; ++j) {
                const float v = bf2f(a.u[j]);
                s += v; ss += v * v;
            }
        }
        stats_reduce(s, ss, SB + bc * 2);
    }
}

// ---------------------------------------------------------------------------
// InstanceNorm stats, single bf16 input.
// ---------------------------------------------------------------------------
__global__ __launch_bounds__(256)
void inorm_stats_kernel(const ushort_t* __restrict__ X, float* __restrict__ stats) {
    const int bc = blockIdx.x;
    const ushort_t* xp = X + (size_t)bc * SDIM;
    float s = 0.f, ss = 0.f;
    for (int i = threadIdx.x * 8; i < SDIM; i += 2048) {
        union { uint4 q; ushort_t u[8]; } a;
        a.q = *(const uint4*)(xp + i);
#pragma unroll
        for (int j = 0; j < 8; ++j) {
            const float v = bf2f(a.u[j]);
            s += v; ss += v * v;
        }
    }
    stats_reduce(s, ss, stats + bc * 2);
}

// ---------------------------------------------------------------------------
// Fused LayerNorm, coalesced: wave handles 8 tokens, butterfly reduce,
// LDS-staged coalesced output.
// ---------------------------------------------------------------------------
__global__ __launch_bounds__(256)
void layernorm_kernel(const ushort_t* __restrict__ C4, const float* __restrict__ stats,
                      const float* __restrict__ X, const float* __restrict__ gam,
                      const float* __restrict__ bet, ushort_t* __restrict__ Tn) {
    const int blk = blockIdx.x;
    const int b = blk >> 7;
    const int tile0 = (blk & 127) * 32;
    const int wv = threadIdx.x >> 6;
    const int lane = threadIdx.x & 63;
    const int l0 = tile0 + wv * 8;

    __shared__ ushort_t tile[32 * 384];

    float v[6][8];
    float s[8], ss[8];
#pragma unroll
    for (int t = 0; t < 8; ++t) { s[t] = 0.f; ss[t] = 0.f; }
    float g[6], be[6];

#pragma unroll
    for (int i = 0; i < 6; ++i) {
        const int c = lane + i * 64;
        g[i] = gam[c]; be[i] = bet[c];
        const size_t base = (size_t)(b * CDIM + c) * SDIM + l0;
        union { uint4 q; ushort_t u[8]; } cv;
        cv.q = *(const uint4*)(C4 + base);
        const float4 x0 = *(const float4*)(X + base);
        const float4 x1 = *(const float4*)(X + base + 4);
        const float xs[8] = {x0.x, x0.y, x0.z, x0.w, x1.x, x1.y, x1.z, x1.w};
        const float m = stats[(b * CDIM + c) * 2];
        const float r = stats[(b * CDIM + c) * 2 + 1];
#pragma unroll
        for (int t = 0; t < 8; ++t) {
            const float val = fmaxf((bf2f(cv.u[t]) - m) * r, 0.f) + xs[t];
            v[i][t] = val;
            s[t] += val; ss[t] += val * val;
        }
    }
#pragma unroll
    for (int off = 32; off > 0; off >>= 1) {
#pragma unroll
        for (int t = 0; t < 8; ++t) {
            s[t] += __shfl_xor(s[t], off);
            ss[t] += __shfl_xor(ss[t], off);
        }
    }
#pragma unroll
    for (int t = 0; t < 8; ++t) {
        const float mean = s[t] * (1.f / CDIM);
        const float rstd = rsqrtf(ss[t] * (1.f / CDIM) - mean * mean + 1e-5f);
        const int trow = (wv * 8 + t) * 384;
#pragma unroll
        for (int i = 0; i < 6; ++i) {
            const int c = lane + i * 64;
            tile[trow + c] = f2bf((v[i][t] - mean) * rstd * g[i] + be[i]);
        }
    }
    __syncthreads();
    uint4* dst = (uint4*)(Tn + ((size_t)b * 4096 + tile0) * CDIM);
    const uint4* srcp = (const uint4*)tile;
#pragma unroll
    for (int k = 0; k < 6; ++k)
        dst[k * 256 + threadIdx.x] = srcp[k * 256 + threadIdx.x];
}

// ---------------------------------------------------------------------------
// Tiled fp32 GEMM for dt_proj (K=24), NT, bias+softplus, bf16 store.
// ---------------------------------------------------------------------------
__global__ __launch_bounds__(256)
void gemm_dtproj_kernel(const float* __restrict__ A, const float* __restrict__ B,
                        ushort_t* __restrict__ C, const float* __restrict__ bias,
                        int M, int N, int K, int lda, int ldb, int ldc) {
    __shared__ __align__(16) float As[16][132];
    __shared__ __align__(16) float Bs[16][68];
    const int t = threadIdx.x;
    const int m0 = blockIdx.y * 128;
    const int n0 = blockIdx.x * 64;

    float acc[8][4];
#pragma unroll
    for (int i = 0; i < 8; ++i)
#pragma unroll
        for (int j = 0; j < 4; ++j) acc[i][j] = 0.f;

    const int mr = (t & 15) * 8;
    const int nr = (t >> 4) * 4;

    for (int k0 = 0; k0 < K; k0 += 16) {
#pragma unroll
        for (int idx = 0; idx < 8; ++idx) {
            const int e = idx * 256 + t;
            const int k = e & 15, m = e >> 4;
            float v = 0.f;
            if (k0 + k < K) v = A[(size_t)(m0 + m) * lda + (k0 + k)];
            As[k][m] = v;
        }
#pragma unroll
        for (int idx = 0; idx < 4; ++idx) {
            const int e = idx * 256 + t;
            const int k = e & 15, n = e >> 4;
            float v = 0.f;
            if ((n0 + n) < N && (k0 + k) < K) v = B[(size_t)(n0 + n) * ldb + (k0 + k)];
            Bs[k][n] = v;
        }
        __syncthreads();
#pragma unroll
        for (int k = 0; k < 16; ++k) {
            float4 a0 = *(const float4*)&As[k][mr];
            float4 a1 = *(const float4*)&As[k][mr + 4];
            float4 b0 = *(const float4*)&Bs[k][nr];
            const float av[8] = {a0.x, a0.y, a0.z, a0.w, a1.x, a1.y, a1.z, a1.w};
            const float bv[4] = {b0.x, b0.y, b0.z, b0.w};
#pragma unroll
            for (int i = 0; i < 8; ++i)
#pragma unroll
                for (int j = 0; j < 4; ++j)
                    acc[i][j] = fmaf(av[i], bv[j], acc[i][j]);
        }
        __syncthreads();
    }

#pragma unroll
    for (int i = 0; i < 8; ++i) {
        const int m = m0 + mr + i;
#pragma unroll
        for (int j = 0; j < 4; ++j) {
            const int n = n0 + nr + j;
            if (n >= N) continue;
            float v = acc[i][j] + bias[n];
            v = (v > 20.f) ? v : log1pf(__expf(v));
            C[(size_t)m * ldc + n] = f2bf(v);
        }
    }
}

// ---------------------------------------------------------------------------
// Causal depthwise conv1d (K=4) + bias + SiLU, bf16 in/out. 4 tokens/thread.
// ---------------------------------------------------------------------------
__global__ __launch_bounds__(256)
void dwconv_silu_kernel(const ushort_t* __restrict__ Xin, const float* __restrict__ W,
                        const float* __restrict__ bias, ushort_t* __restrict__ U) {
    const int dch = blockIdx.x * 256 + threadIdx.x;
    const int l0 = blockIdx.y * 4, b = blockIdx.z;
    const float4 w4 = ((const float4*)W)[dch];
    const float wk[4] = {w4.x, w4.y, w4.z, w4.w};
    const float bs = bias[dch];
    const size_t base = ((size_t)b * 4096 + l0) * DINC + dch;
    float r[7];
#pragma unroll
    for (int k = 0; k < 7; ++k) {
        const int ll = l0 - 3 + k;
        r[k] = (ll >= 0) ? bf2f(Xin[base + (size_t)(k - 3) * DINC]) : 0.f;
    }
#pragma unroll
    for (int j = 0; j < 4; ++j) {
        float acc = bs;
#pragma unroll
        for (int k = 0; k < 4; ++k) acc = fmaf(r[j + k], wk[k], acc);
        U[base + (size_t)j * DINC] = f2bf(acc / (1.f + __expf(-acc)));
    }
}

// ---------------------------------------------------------------------------
// Chunked parallel selective scan (3 phases). dt/u/z/y bf16; B,C fp32.
// ---------------------------------------------------------------------------
__global__ __launch_bounds__(256)
void scan_phase1_kernel(const ushort_t* __restrict__ DT, const ushort_t* __restrict__ U,
                        const float* __restrict__ DBL, const float* __restrict__ A_log,
                        float* __restrict__ HOUT, float* __restrict__ SDT) {
    const int b = blockIdx.z, chunk = blockIdx.y;
    const int dch = blockIdx.x * 256 + threadIdx.x;
    float Arow[16];
#pragma unroll
    for (int n = 0; n < NST; ++n) Arow[n] = -__expf(A_log[dch * NST + n]);

    __shared__ float bcs[LCHUNK][16];
    const size_t tokbase = (size_t)b * 4096 + chunk * LCHUNK;
#pragma unroll
    for (int idx = 0; idx < 4; ++idx) {
        const int e = idx * 256 + threadIdx.x;
        bcs[e >> 4][e & 15] = DBL[(tokbase + (e >> 4)) * 56 + 24 + (e & 15)];
    }
    __syncthreads();

    size_t off = tokbase * DINC + dch;
    float h[16];
#pragma unroll
    for (int n = 0; n < NST; ++n) h[n] = 0.f;
    float sdt = 0.f;
    float cdt = bf2f(DT[off]), cu = bf2f(U[off]);
    for (int t = 0; t < LCHUNK; ++t) {
        float ndt = 0.f, nu = 0.f;
        if (t < LCHUNK - 1) { ndt = bf2f(DT[off + DINC]); nu = bf2f(U[off + DINC]); }
        sdt += cdt;
        const float du = cdt * cu;
#pragma unroll
        for (int n = 0; n < NST; ++n)
            h[n] = __expf(cdt * Arow[n]) * h[n] + du * bcs[t][n];
        off += DINC;
        cdt = ndt; cu = nu;
    }
    float* hp = HOUT + (((size_t)(b * DINC + dch) * NCHUNK + chunk) << 4);
#pragma unroll
    for (int n = 0; n < NST; ++n) hp[n] = h[n];
    SDT[(size_t)(b * DINC + dch) * NCHUNK + chunk] = sdt;
}

__global__ __launch_bounds__(256)
void scan_phase2_kernel(float* __restrict__ HOUT, const float* __restrict__ SDT,
                        const float* __restrict__ A_log) {
    const int t = blockIdx.x * 256 + threadIdx.x;        // 49152
    const int b = t / (DINC * NST);
    const int rem = t - b * (DINC * NST);
    const int d = rem >> 4, n = rem & 15;
    const float An = -__expf(A_log[d * NST + n]);
    float* hp = HOUT + (((size_t)(b * DINC + d) * NCHUNK) << 4) + n;
    const float* sp = SDT + (size_t)(b * DINC + d) * NCHUNK;
    float H = 0.f;
    for (int c = 0; c < NCHUNK; ++c) {
        const float tmp = hp[c * 16];
        const float dA = __expf(An * sp[c]);
        hp[c * 16] = H;
        H = dA * H + tmp;
    }
}

__global__ __launch_bounds__(256)
void scan_phase3_kernel(ushort_t* __restrict__ DT, const ushort_t* __restrict__ U,
                        const float* __restrict__ DBL, const ushort_t* __restrict__ Z,
                        const float* __restrict__ A_log, const float* __restrict__ D_skip,
                        const float* __restrict__ HOUT) {
    const int b = blockIdx.z, chunk = blockIdx.y;
    const int dch = blockIdx.x * 256 + threadIdx.x;
    float Arow[16];
#pragma unroll
    for (int n = 0; n < NST; ++n) Arow[n] = -__expf(A_log[dch * NST + n]);
    const float Dsk = D_skip[dch];

    __shared__ float bcs[LCHUNK][32];
    const size_t tokbase = (size_t)b * 4096 + chunk * LCHUNK;
#pragma unroll
    for (int idx = 0; idx < 8; ++idx) {
        const int e = idx * 256 + threadIdx.x;
        bcs[e >> 5][e & 31] = DBL[(tokbase + (e >> 5)) * 56 + 24 + (e & 31)];
    }
    __syncthreads();

    float h[16];
    const float* hp = HOUT + (((size_t)(b * DINC + dch) * NCHUNK + chunk) << 4);
#pragma unroll
    for (int n = 0; n < NST; ++n) h[n] = hp[n];

    size_t off = tokbase * DINC + dch;
    float cdt = bf2f(DT[off]), cu = bf2f(U[off]), cz = bf2f(Z[off]);
    for (int t = 0; t < LCHUNK; ++t) {
        float ndt = 0.f, nu = 0.f, nz = 0.f;
        if (t < LCHUNK - 1) {
            ndt = bf2f(DT[off + DINC]); nu = bf2f(U[off + DINC]); nz = bf2f(Z[off + DINC]);
        }
        const float du = cdt * cu;
        float y = 0.f;
#pragma unroll
        for (int n = 0; n < NST; ++n) {
            h[n] = __expf(cdt * Arow[n]) * h[n] + du * bcs[t][n];
            y = fmaf(h[n], bcs[t][16 + n], y);
        }
        y += cu * Dsk;
        const float sz = cz / (1.f + __expf(-cz));
        DT[off] = f2bf(y * sz);
        off += DINC;
        cdt = ndt; cu = nu; cz = nz;
    }
}

// ---------------------------------------------------------------------------
extern "C" void kernel_launch(void* const* d_in, const int* in_sizes, int n_in,
                              void* d_out, int out_size, void* d_ws, size_t ws_size,
                              hipStream_t stream) {
    (void)in_sizes; (void)n_in; (void)out_size; (void)ws_size;
    const float* x         = (const float*)d_in[0];
    const float* w1        = (const float*)d_in[1];
    const float* w2        = (const float*)d_in[3];
    const float* w3        = (const float*)d_in[5];
    const float* w4        = (const float*)d_in[7];
    const float* ln_g      = (const float*)d_in[9];
    const float* ln_b      = (const float*)d_in[10];
    const float* in_proj_w = (const float*)d_in[11];
    const float* conv1d_w  = (const float*)d_in[12];
    const float* conv1d_b  = (const float*)d_in[13];
    const float* x_proj_w  = (const float*)d_in[14];
    const float* dt_proj_w = (const float*)d_in[15];
    const float* dt_proj_b = (const float*)d_in[16];
    const float* A_log     = (const float*)d_in[17];
    const float* D_skip    = (const float*)d_in[18];
    const float* out_proj_w= (const float*)d_in[19];
    float* out = (float*)d_out;

    // Workspace regions (floats): R0..R4. Lifetimes disjoint where aliased.
    float* ws = (float*)d_ws;
    float* R0 = ws;                    //  6291456
    float* R1 = ws + 6291456;          //  6291456
    float* R2 = ws + 12582912;         // 12582912
    float* R3 = ws + 25165824;         // 12582912
    float* R4 = ws + 37748736;         // 12582912

    // GSC-phase aliases (conv partials/outputs bf16)
    ushort_t* P0    = (ushort_t*)R0;                 // partial z=0
    ushort_t* P1    = P0 + PSTRIDE;                  // partial z=1
    ushort_t* C34   = (ushort_t*)R3;                 // c3/c4 outputs bf16
    ushort_t* Wb1   = (ushort_t*)R2;                 // 3981312 bf16
    ushort_t* Xp    = (ushort_t*)(R2 + 2097152);     // 8957952 bf16
    ushort_t* w3b   = (ushort_t*)(R2 + 6576128);     // 147456 bf16
    ushort_t* w4b   = (ushort_t*)(R2 + 6649856);     // 147456 bf16
    ushort_t* Wb2   = (ushort_t*)(R2 + 6723584);     // 3981312 bf16
    float*    SA    = R4;                            // stats A
    float*    SB    = R4 + 4096;                     // stats B
    ushort_t* ipwb  = (ushort_t*)(R4 + 6291456);
    ushort_t* opwb  = (ushort_t*)(R4 + 6586368);
    ushort_t* xpwb  = (ushort_t*)(R4 + 6733824);
    // Mamba-phase aliases
    ushort_t* tnb   = (ushort_t*)R0;                 // 16384*384 bf16
    float*    DBL   = R0 + 3145728;                  // 16384*56 fp32
    float*    HOUT  = R1;
    float*    SDT   = R1 + 3145728;
    ushort_t* XIN   = (ushort_t*)R2;
    ushort_t* Zb    = (ushort_t*)R3;
    ushort_t* Ub    = (ushort_t*)R4;
    ushort_t* DTb   = (ushort_t*)R2;

    const size_t XP_BYTES = (size_t)4 * 18 * 18 * 18 * CDIM * 2;

    // ---- upfront: zero pad borders, convert all weights, pad x ----
    hipMemsetAsync(Xp, 0, XP_BYTES, stream);
    prep_weights_kernel<<<2346, 256, 0, stream>>>(
        w1, w2, w3, w4, in_proj_w, out_proj_w, x_proj_w,
        Wb1, Wb2, w3b, w4b, ipwb, opwb, xpwb);
    pad_kernel<<<1024, 384, 0, stream>>>(x, Xp);
    // ---- c1 (3x3x3 z-split) + c3 (1x1) fused; 512-thread 128x256 blocks ----
    conv_kernel<1><<<576, 512, 0, stream>>>(Xp, Wb1, w3b, P0, C34);
    inorm_stats_combo_kernel<<<3072, 256, 0, stream>>>(P0, P1, SA, C34, SB);
    pad_fuse2_kernel<<<1024, 384, 0, stream>>>(P0, P1, SA, Xp);             // x1a
    // ---- c2 ----
    conv_kernel<0><<<384, 512, 0, stream>>>(Xp, Wb2, nullptr, P0, nullptr);
    inorm_stats_combo_kernel<<<1536, 256, 0, stream>>>(P0, P1, SA, nullptr, nullptr);
    pad_fuse3_kernel<<<1024, 384, 0, stream>>>(P0, P1, SA, C34, SB, Xp);    // S
    // ---- c4 (1x1) ----
    conv_kernel<2><<<192, 512, 0, stream>>>(Xp, nullptr, w4b, nullptr, C34);
    inorm_stats_kernel<<<1536, 256, 0, stream>>>(C34, SA);
    // ---- fused relu(IN(c4)) + x residual + LayerNorm -> tn bf16 [b][l][c]
    layernorm_kernel<<<512, 256, 0, stream>>>(C34, SA, x, ln_g, ln_b, tnb);
    // ---- in_proj (bf16 MFMA, gl_lds+prefetch): tn x W^T -> XIN | Zb (bf16)
    gemm_gl_kernel<1><<<1536, 256, 0, stream>>>(
        tnb, ipwb, XIN, Zb, 16384, 1536, CDIM, 0, 12);
    // ---- causal depthwise conv + SiLU -> Ub (bf16)
    dwconv_silu_kernel<<<dim3(3, 1024, 4), 256, 0, stream>>>(XIN, conv1d_w, conv1d_b, Ub);
    // ---- x_proj (bf16 MFMA, N=56 masked): u x W^T -> DBL (fp32)
    gemm_gl_kernel<0><<<128, 256, 0, stream>>>(
        Ub, xpwb, DBL, nullptr, 16384, 56, DINC, 56, 1);
    // ---- dt_proj (fp32 VALU, K=24) + bias + softplus -> DTb (bf16)
    gemm_dtproj_kernel<<<dim3(12, 128), 256, 0, stream>>>(
        DBL, dt_proj_w, DTb, dt_proj_b, 16384, DINC, 24, 56, 24, DINC);
    // ---- chunked parallel selective scan (y bf16 over DTb)
    scan_phase1_kernel<<<dim3(3, NCHUNK, 4), 256, 0, stream>>>(
        DTb, Ub, DBL, A_log, HOUT, SDT);
    scan_phase2_kernel<<<192, 256, 0, stream>>>(HOUT, SDT, A_log);
    scan_phase3_kernel<<<dim3(3, NCHUNK, 4), 256, 0, stream>>>(
        DTb, Ub, DBL, Zb, A_log, D_skip, HOUT);
    // ---- out_proj (bf16 MFMA) -> d_out transposed fp32
    gemm_gl_kernel<2><<<384, 256, 0, stream>>>(
        DTb, opwb, out, nullptr, 16384, CDIM, DINC, 0, 3);
}

// Round 15
// 722.087 us; speedup vs baseline: 1.1450x; 1.0208x over previous
//
#include <hip/hip_runtime.h>
#include <math.h>

#define CDIM 384
#define SDIM 4096
#define BDIM 4
#define DINC 768
#define NST  16
#define NCHUNK 64
#define LCHUNK 64
#define PSTRIDE 6291456   // ELEMENTS per conv partial [B,C,S] (bf16)

typedef unsigned short ushort_t;
typedef unsigned int uint_t;
typedef __attribute__((ext_vector_type(4))) float f32x4;
typedef __attribute__((ext_vector_type(8))) short bf16x8;

__device__ __forceinline__ ushort_t f2bf(float f) {
    union { float f; uint_t u; } v; v.f = f;
    uint_t r = v.u + 0x7FFFu + ((v.u >> 16) & 1u);   // round-to-nearest-even
    return (ushort_t)(r >> 16);
}
__device__ __forceinline__ float bf2f(ushort_t u) {
    union { uint_t i; float f; } v; v.i = ((uint_t)u) << 16; return v.f;
}
__device__ __forceinline__ uint_t pk2(float a, float b) {
    return (uint_t)f2bf(a) | ((uint_t)f2bf(b) << 16);
}
// async global->LDS, 16B per lane, dest = wave-uniform base + lane*16
__device__ __forceinline__ void gl16(const ushort_t* g, ushort_t* l) {
    __builtin_amdgcn_global_load_lds(
        (const __attribute__((address_space(1))) void*)(g),
        (__attribute__((address_space(3))) void*)(l), 16, 0, 0);
}

// ---------------------------------------------------------------------------
// Merged weight prep: all fp32->bf16 weight conversions in one dispatch.
// ---------------------------------------------------------------------------
__device__ __forceinline__ void wconv_body(const float* __restrict__ W,
                                           ushort_t* __restrict__ Wb, int idx) {
    const float* wp = W + (size_t)idx * 27;              // idx = co*384+ci
#pragma unroll
    for (int tap = 0; tap < 27; ++tap)
        Wb[(size_t)tap * (CDIM * CDIM) + idx] = f2bf(wp[tap]);
}
__device__ __forceinline__ void cvt_body(const float* __restrict__ src,
                                         ushort_t* __restrict__ dst, int i) {
    float4 v = ((const float4*)src)[i];
    uint2 o; o.x = pk2(v.x, v.y); o.y = pk2(v.z, v.w);
    ((uint2*)dst)[i] = o;
}
__global__ __launch_bounds__(256)
void prep_weights_kernel(const float* w1, const float* w2, const float* w3,
                         const float* w4, const float* ipw, const float* opw,
                         const float* xpw,
                         ushort_t* Wb1, ushort_t* Wb2, ushort_t* w3b, ushort_t* w4b,
                         ushort_t* ipwb, ushort_t* opwb, ushort_t* xpwb) {
    const int bid = blockIdx.x, t = threadIdx.x;
    if      (bid < 576)  wconv_body(w1, Wb1, bid * 256 + t);
    else if (bid < 1152) wconv_body(w2, Wb2, (bid - 576) * 256 + t);
    else if (bid < 1296) cvt_body(w3, w3b, (bid - 1152) * 256 + t);
    else if (bid < 1440) cvt_body(w4, w4b, (bid - 1296) * 256 + t);
    else if (bid < 2016) cvt_body(ipw, ipwb, (bid - 1440) * 256 + t);
    else if (bid < 2304) cvt_body(opw, opwb, (bid - 2016) * 256 + t);
    else                 cvt_body(xpw, xpwb, (bid - 2304) * 256 + t);
}

// ---------------------------------------------------------------------------
// Pad + transpose to channels-last bf16: src[b][c][16^3] -> Xp[b][18][18][18][384]
// ---------------------------------------------------------------------------
__global__ __launch_bounds__(384)
void pad_kernel(const float* __restrict__ src, ushort_t* __restrict__ Xp) {
    const int blk = blockIdx.x;                          // b(4) d(16) h(16)
    const int b = blk >> 8, d = (blk >> 4) & 15, h = blk & 15;
    const int ci = threadIdx.x;
    const float* sp = src + (size_t)(b * CDIM + ci) * SDIM + d * 256 + h * 16;
    ushort_t* dp = Xp + ((((size_t)(b * 18 + d + 1) * 18) + (h + 1)) * 18 + 1) * CDIM + ci;
#pragma unroll
    for (int w = 0; w < 16; ++w)
        dp[(size_t)w * CDIM] = f2bf(sp[w]);
}

// ---------------------------------------------------------------------------
// Fused: v = relu((P0+P1 - m)*r) -> pad/transpose channels-last bf16 Xp.
// ---------------------------------------------------------------------------
__global__ __launch_bounds__(384)
void pad_fuse2_kernel(const ushort_t* __restrict__ P0, const ushort_t* __restrict__ P1,
                      const float* __restrict__ stats, ushort_t* __restrict__ Xp) {
    const int blk = blockIdx.x;
    const int b = blk >> 8, d = (blk >> 4) & 15, h = blk & 15;
    const int ci = threadIdx.x;
    const size_t o = (size_t)(b * CDIM + ci) * SDIM + d * 256 + h * 16;
    const float m = stats[(b * CDIM + ci) * 2], r = stats[(b * CDIM + ci) * 2 + 1];
    union { uint4 q[2]; ushort_t u[16]; } a, c;
    a.q[0] = ((const uint4*)(P0 + o))[0]; a.q[1] = ((const uint4*)(P0 + o))[1];
    c.q[0] = ((const uint4*)(P1 + o))[0]; c.q[1] = ((const uint4*)(P1 + o))[1];
    ushort_t* dp = Xp + ((((size_t)(b * 18 + d + 1) * 18) + (h + 1)) * 18 + 1) * CDIM + ci;
#pragma unroll
    for (int w = 0; w < 16; ++w) {
        const float v = bf2f(a.u[w]) + bf2f(c.u[w]);
        dp[(size_t)w * CDIM] = f2bf(fmaxf((v - m) * r, 0.f));
    }
}

// ---------------------------------------------------------------------------
// Fused: S = relu((P0+P1-m2)*r2) + relu((C3-m3)*r3) -> pad channels-last bf16.
// ---------------------------------------------------------------------------
__global__ __launch_bounds__(384)
void pad_fuse3_kernel(const ushort_t* __restrict__ P0, const ushort_t* __restrict__ P1,
                      const float* __restrict__ st2, const ushort_t* __restrict__ C3,
                      const float* __restrict__ st3, ushort_t* __restrict__ Xp) {
    const int blk = blockIdx.x;
    const int b = blk >> 8, d = (blk >> 4) & 15, h = blk & 15;
    const int ci = threadIdx.x;
    const size_t o = (size_t)(b * CDIM + ci) * SDIM + d * 256 + h * 16;
    const float m2 = st2[(b * CDIM + ci) * 2], r2 = st2[(b * CDIM + ci) * 2 + 1];
    const float m3 = st3[(b * CDIM + ci) * 2], r3 = st3[(b * CDIM + ci) * 2 + 1];
    union { uint4 q[2]; ushort_t u[16]; } a, c, e;
    a.q[0] = ((const uint4*)(P0 + o))[0]; a.q[1] = ((const uint4*)(P0 + o))[1];
    c.q[0] = ((const uint4*)(P1 + o))[0]; c.q[1] = ((const uint4*)(P1 + o))[1];
    e.q[0] = ((const uint4*)(C3 + o))[0]; e.q[1] = ((const uint4*)(C3 + o))[1];
    ushort_t* dp = Xp + ((((size_t)(b * 18 + d + 1) * 18) + (h + 1)) * 18 + 1) * CDIM + ci;
#pragma unroll
    for (int w = 0; w < 16; ++w) {
        const float x1 = fmaxf((bf2f(a.u[w]) + bf2f(c.u[w]) - m2) * r2, 0.f);
        const float x2 = fmaxf((bf2f(e.u[w]) - m3) * r3, 0.f);
        dp[(size_t)w * CDIM] = f2bf(x1 + x2);
    }
}

// ---------------------------------------------------------------------------
// Implicit-GEMM conv via MFMA bf16: 512 threads (8 waves, 2co x 4sp),
// block 128co x 256sp, gl_lds staging, XOR-swizzled content, and T4
// counted-vmcnt double-buffer pipeline: stage(buf^1) -> s_waitcnt vmcnt(3)
// (own previous-buffer loads only; prefetch stays in flight) -> raw
// s_barrier -> ds_read+MFMA(buf) -> raw s_barrier (no drain). LDS 48KB.
// MODE 0: c2 (z in {0,1} tap-split -> Y01+z*PSTRIDE)
// MODE 1: c1 (z in {0,1}) + c3 1x1 fused as z==2 (W3 -> Y2)
// MODE 2: pure 1x1 (c4 -> Y2)
// ---------------------------------------------------------------------------
template<int MODE>
__global__ __launch_bounds__(512)
void conv_kernel(const ushort_t* __restrict__ Xp, const ushort_t* __restrict__ Wb,
                 const ushort_t* __restrict__ W3, ushort_t* __restrict__ Y01,
                 ushort_t* __restrict__ Y2) {
    const int wid = blockIdx.x;
    const int ntid = wid & 63;                           // (b,d) innermost
    const int rest = wid >> 6;
    const int co0 = (rest % 3) * 128;
    const int zz  = rest / 3;
    const int b  = ntid >> 4;
    const int d  = ntid & 15;
    const int t = threadIdx.x;
    const int lane = t & 63;
    const int wv = t >> 6;                               // 0..7
    const int wy = wv >> 2, wx = wv & 3;                 // co-half / sp-quarter

    const bool is1x1 = (MODE == 2) || (MODE == 1 && zz == 2);
    const ushort_t* Wsrc; int tap0, iters, kd0, kh0, kw0; ushort_t* Y;
    if (is1x1) {
        Wsrc = W3; tap0 = 0; iters = 12; kd0 = 1; kh0 = 1; kw0 = 1; Y = Y2;
    } else {
        Wsrc = Wb; tap0 = zz ? 14 : 0; iters = (zz ? 13 : 14) * 12;
        kd0 = zz ? 1 : 0; kh0 = zz ? 1 : 0; kw0 = zz ? 2 : 0;
        Y = Y01 + (size_t)zz * PSTRIDE;
    }

    __shared__ __align__(16) ushort_t As[2][4096];       // [128][32] bf16 x2, 16KB
    __shared__ __align__(16) ushort_t Bs[2][8192];       // [256][32] bf16 x2, 32KB

    f32x4 acc[4][4];
#pragma unroll
    for (int i = 0; i < 4; ++i)
#pragma unroll
        for (int j = 0; j < 4; ++j) acc[i][j] = (f32x4){0.f, 0.f, 0.f, 0.f};

    // staging thread-constants (per-lane, fixed): swizzled source granule
    const int l4 = lane >> 2;
    const int cg = (((lane & 3) ^ ((lane >> 3) & 3)) << 3);
    const int rA = wv * 16 + l4;                         // A row (1 instr/wave)
    const int aTC = (co0 + rA) * CDIM + cg;
    int bTC[2];
#pragma unroll
    for (int i = 0; i < 2; ++i) {
        const int r = wv * 32 + i * 16 + l4;             // B row (2 instr/wave)
        bTC[i] = ((r >> 4) * 18 + (r & 15)) * CDIM + cg;
    }

    // uniform walking offsets
    int aoff = tap0 * (CDIM * CDIM);
    int goff = (((b * 18 + d + kd0) * 18 + kh0) * 18 + kw0) * CDIM;
    int c12 = 0, ckw = kw0, ckh = kh0;

    // fragment read bases (same XOR involution as writes)
    const int lm = lane & 15;
    const int sw8 = (((lane >> 4) ^ ((lm >> 1) & 3)) << 3);
    const int rA0 = (wy * 64 + lm) * 32 + sw8;           // + mi*512
    const int rB0 = (wx * 64 + lm) * 32 + sw8;           // + ni*512

    auto stage = [&](int bf) {                           // 3 gl_lds per wave + walk
        ushort_t* la = &As[bf][wv * 512];
        ushort_t* lb = &Bs[bf][wv * 1024];
        gl16(Wsrc + aoff + aTC, la);
        gl16(Xp + goff + bTC[0], lb);
        gl16(Xp + goff + bTC[1], lb + 512);
        aoff += 32; goff += 32;
        if (++c12 == 12) {                               // tap wrap
            c12 = 0;
            aoff += CDIM * CDIM - CDIM;
            if (++ckw == 3) {
                ckw = 0;
                if (++ckh == 3) { ckh = 0; goff += 109440; }
                else goff += 5760;
            }
        }
    };

    stage(0);
    asm volatile("s_waitcnt vmcnt(0)" ::: "memory");
    __builtin_amdgcn_s_barrier();                        // buf0 ready everywhere

    int buf = 0;
    for (int idx = 0; idx < iters; ++idx) {
        const bool more = (idx + 1) < iters;
        if (more) {
            stage(buf ^ 1);                              // prefetch next tile
            asm volatile("s_waitcnt vmcnt(3)" ::: "memory");  // prev-buf loads done
        } else {
            asm volatile("s_waitcnt vmcnt(0)" ::: "memory");
        }
        __builtin_amdgcn_s_barrier();                    // all waves' buf data landed
        __builtin_amdgcn_sched_barrier(0);               // pin: no hoist above wait
        bf16x8 af[4], bfr[4];
#pragma unroll
        for (int mi = 0; mi < 4; ++mi)
            af[mi] = *reinterpret_cast<const bf16x8*>(&As[buf][rA0 + mi * 512]);
#pragma unroll
        for (int ni = 0; ni < 4; ++ni)
            bfr[ni] = *reinterpret_cast<const bf16x8*>(&Bs[buf][rB0 + ni * 512]);
#pragma unroll
        for (int mi = 0; mi < 4; ++mi)
#pragma unroll
            for (int ni = 0; ni < 4; ++ni)
                acc[mi][ni] = __builtin_amdgcn_mfma_f32_16x16x32_bf16(
                    af[mi], bfr[ni], acc[mi][ni], 0, 0, 0);
        __builtin_amdgcn_s_barrier();                    // reads done; NO vmcnt drain
        buf ^= 1;
    }

    // epilogue: C/D layout col(lane&15)=sp, row=(lane>>4)*4+j=co; bf16 store
    const int coB = co0 + wy * 64 + (lane >> 4) * 4;
#pragma unroll
    for (int mi = 0; mi < 4; ++mi) {
#pragma unroll
        for (int ni = 0; ni < 4; ++ni) {
            const int nl = wx * 64 + ni * 16 + lm;       // sp within plane
            const int s = d * 256 + nl;
            ushort_t* yp = Y + ((size_t)b * CDIM + (coB + mi * 16)) * SDIM + s;
#pragma unroll
            for (int j = 0; j < 4; ++j)
                yp[(size_t)j * SDIM] = f2bf(acc[mi][ni][j]);
        }
    }
}

// ---------------------------------------------------------------------------
// bf16 MFMA GEMM NT with gl_lds + 2-phase prefetch (proven, unchanged).
// C[M,N] = A[M,K] x B[N,K]^T. N masked via address clamp + store mask.
// EPI 0: fp32 store (ldc); 1: xz split -> bf16 C/C2 (N=1536);
// 2: transposed fp32 float4 store C[b][n][l].
// ---------------------------------------------------------------------------
template<int EPI>
__global__ __launch_bounds__(256)
void gemm_gl_kernel(const ushort_t* __restrict__ A, const ushort_t* __restrict__ Bw,
                    void* __restrict__ Cv, void* __restrict__ C2v,
                    int M, int N, int K, int ldc, int nx) {
    const int wid = blockIdx.x;
    const int n0 = (wid % nx) * 128;
    const int m0 = (wid / nx) * 128;
    const int t = threadIdx.x;
    const int lane = t & 63;
    const int wv = t >> 6;
    const int wy = wv >> 1, wx = wv & 1;

    __shared__ __align__(16) ushort_t As[2][4096];
    __shared__ __align__(16) ushort_t Bs[2][4096];

    f32x4 acc[4][4];
#pragma unroll
    for (int i = 0; i < 4; ++i)
#pragma unroll
        for (int j = 0; j < 4; ++j) acc[i][j] = (f32x4){0.f, 0.f, 0.f, 0.f};

    const int l4 = lane >> 2;
    const int cg = (((lane & 3) ^ ((lane >> 3) & 3)) << 3);
    size_t aTC[2], bTC[2];
#pragma unroll
    for (int i = 0; i < 2; ++i) {
        const int r = wv * 32 + i * 16 + l4;
        aTC[i] = (size_t)(m0 + r) * K + cg;
        int br = n0 + r; if (br >= N) br = N - 1;        // clamp (masked at store)
        bTC[i] = (size_t)br * K + cg;
    }

    const int lm = lane & 15;
    const int sw8 = (((lane >> 4) ^ ((lm >> 1) & 3)) << 3);
    const int rA0 = (wy * 64 + lm) * 32 + sw8;
    const int rB0 = (wx * 64 + lm) * 32 + sw8;

    auto stage = [&](int bf, int ko) {
        ushort_t* la = &As[bf][wv * 1024];
        ushort_t* lb = &Bs[bf][wv * 1024];
        gl16(A + aTC[0] + ko, la);
        gl16(A + aTC[1] + ko, la + 512);
        gl16(Bw + bTC[0] + ko, lb);
        gl16(Bw + bTC[1] + ko, lb + 512);
    };

    const int KI = K >> 5;
    stage(0, 0);
    __syncthreads();

    int buf = 0;
    for (int kk = 0; kk < KI; ++kk) {
        if (kk + 1 < KI) stage(buf ^ 1, (kk + 1) * 32);
        bf16x8 af[4], bfr[4];
#pragma unroll
        for (int mi = 0; mi < 4; ++mi)
            af[mi] = *reinterpret_cast<const bf16x8*>(&As[buf][rA0 + mi * 512]);
#pragma unroll
        for (int ni = 0; ni < 4; ++ni)
            bfr[ni] = *reinterpret_cast<const bf16x8*>(&Bs[buf][rB0 + ni * 512]);
#pragma unroll
        for (int mi = 0; mi < 4; ++mi)
#pragma unroll
            for (int ni = 0; ni < 4; ++ni)
                acc[mi][ni] = __builtin_amdgcn_mfma_f32_16x16x32_bf16(
                    af[mi], bfr[ni], acc[mi][ni], 0, 0, 0);
        __syncthreads();
        buf ^= 1;
    }

    const int mB = m0 + wy * 64 + (lane >> 4) * 4;
    const int nB = n0 + wx * 64 + lm;
#pragma unroll
    for (int mi = 0; mi < 4; ++mi) {
#pragma unroll
        for (int ni = 0; ni < 4; ++ni) {
            const int n = nB + ni * 16;
            if (EPI == 2) {                              // transposed float4
                const int mrow = mB + mi * 16;
                const int bb = mrow >> 12, l = mrow & 4095;
                float4 st = {acc[mi][ni][0], acc[mi][ni][1],
                             acc[mi][ni][2], acc[mi][ni][3]};
                *reinterpret_cast<float4*>(
                    (float*)Cv + ((size_t)(bb * CDIM + n)) * SDIM + l) = st;
            } else {
#pragma unroll
                for (int j = 0; j < 4; ++j) {
                    const int m = mB + mi * 16 + j;
                    const float v = acc[mi][ni][j];
                    if (EPI == 0) {
                        if (n < N) ((float*)Cv)[(size_t)m * ldc + n] = v;
                    } else {                             // xz split, bf16 out
                        if (n < DINC) ((ushort_t*)Cv)[(size_t)m * DINC + n] = f2bf(v);
                        else ((ushort_t*)C2v)[(size_t)m * DINC + (n - DINC)] = f2bf(v);
                    }
                }
            }
        }
    }
}

// ---------------------------------------------------------------------------
// Reduction helper for instance-norm stats.
// ---------------------------------------------------------------------------
__device__ __forceinline__ void stats_reduce(float s, float ss, float* out) {
#pragma unroll
    for (int off = 32; off > 0; off >>= 1) {
        s += __shfl_down(s, off);
        ss += __shfl_down(ss, off);
    }
    __shared__ float rs[4], rss[4];
    const int wid = threadIdx.x >> 6;
    if ((threadIdx.x & 63) == 0) { rs[wid] = s; rss[wid] = ss; }
    __syncthreads();
    if (threadIdx.x == 0) {
        float S = rs[0] + rs[1] + rs[2] + rs[3];
        float SS = rss[0] + rss[1] + rss[2] + rss[3];
        float m = S * (1.f / SDIM);
        float var = SS * (1.f / SDIM) - m * m;
        out[0] = m;
        out[1] = rsqrtf(var + 1e-5f);
    }
}

// ---------------------------------------------------------------------------
// Combo stats (bf16 inputs): bc<1536 -> stats of (P0+P1) into SA;
// bc>=1536 -> stats of X3 into SB (only when grid > 1536).
// ---------------------------------------------------------------------------
__global__ __launch_bounds__(256)
void inorm_stats_combo_kernel(const ushort_t* __restrict__ P0,
                              const ushort_t* __restrict__ P1,
                              float* __restrict__ SA,
                              const ushort_t* __restrict__ X3,
                              float* __restrict__ SB) {
    const int bid = blockIdx.x;
    float s = 0.f, ss = 0.f;
    if (bid < 1536) {
        const ushort_t* p0 = P0 + (size_t)bid * SDIM;
        const ushort_t* p1 = P1 + (size_t)bid * SDIM;
        for (int i = threadIdx.x * 8; i < SDIM; i += 2048) {
            union { uint4 q; ushort_t u[8]; } a, c;
            a.q = *(const uint4*)(p0 + i);
            c.q = *(const uint4*)(p1 + i);
#pragma unroll
            for (int j = 0; j < 8; ++j) {
                const float v = bf2f(a.u[j]) + bf2f(c.u[j]);
                s += v; ss += v * v;
            }
        }
        stats_reduce(s, ss, SA + bid * 2);
    } else {
        const int bc = bid - 1536;
        const ushort_t* xp = X3 + (size_t)bc * SDIM;
        for (int i = threadIdx.x * 8; i < SDIM; i += 2048) {
            union { uint4 q; ushort_t u[8]; } a;
            a.q = *(const uint4*)(xp + i);
#pragma unroll
            for (int j = 0; j < 8; ++j) {
                const float v = bf2f(a.u[j]);
                s += v; ss += v * v;
            }
        }
        stats_reduce(s, ss, SB + bc * 2);
    }
}

// ---------------------------------------------------------------------------
// InstanceNorm stats, single bf16 input.
// ---------------------------------------------------------------------------
__global__ __launch_bounds__(256)
void inorm_stats_kernel(const ushort_t* __restrict__ X, float* __restrict__ stats) {
    const int bc = blockIdx.x;
    const ushort_t* xp = X + (size_t)bc * SDIM;
    float s = 0.f, ss = 0.f;
    for (int i = threadIdx.x * 8; i < SDIM; i += 2048) {
        union { uint4 q; ushort_t u[8]; } a;
        a.q = *(const uint4*)(xp + i);
#pragma unroll
        for (int j = 0; j < 8; ++j) {
            const float v = bf2f(a.u[j]);
            s += v; ss += v * v;
        }
    }
    stats_reduce(s, ss, stats + bc * 2);
}

// ---------------------------------------------------------------------------
// Fused LayerNorm, coalesced: wave handles 8 tokens, butterfly reduce,
// LDS-staged coalesced output.
// ---------------------------------------------------------------------------
__global__ __launch_bounds__(256)
void layernorm_kernel(const ushort_t* __restrict__ C4, const float* __restrict__ stats,
                      const float* __restrict__ X, const float* __restrict__ gam,
                      const float* __restrict__ bet, ushort_t* __restrict__ Tn) {
    const int blk = blockIdx.x;
    const int b = blk >> 7;
    const int tile0 = (blk & 127) * 32;
    const int wv = threadIdx.x >> 6;
    const int lane = threadIdx.x & 63;
    const int l0 = tile0 + wv * 8;

    __shared__ ushort_t tile[32 * 384];

    float v[6][8];
    float s[8], ss[8];
#pragma unroll
    for (int t = 0; t < 8; ++t) { s[t] = 0.f; ss[t] = 0.f; }
    float g[6], be[6];

#pragma unroll
    for (int i = 0; i < 6; ++i) {
        const int c = lane + i * 64;
        g[i] = gam[c]; be[i] = bet[c];
        const size_t base = (size_t)(b * CDIM + c) * SDIM + l0;
        union { uint4 q; ushort_t u[8]; } cv;
        cv.q = *(const uint4*)(C4 + base);
        const float4 x0 = *(const float4*)(X + base);
        const float4 x1 = *(const float4*)(X + base + 4);
        const float xs[8] = {x0.x, x0.y, x0.z, x0.w, x1.x, x1.y, x1.z, x1.w};
        const float m = stats[(b * CDIM + c) * 2];
        const float r = stats[(b * CDIM + c) * 2 + 1];
#pragma unroll
        for (int t = 0; t < 8; ++t) {
            const float val = fmaxf((bf2f(cv.u[t]) - m) * r, 0.f) + xs[t];
            v[i][t] = val;
            s[t] += val; ss[t] += val * val;
        }
    }
#pragma unroll
    for (int off = 32; off > 0; off >>= 1) {
#pragma unroll
        for (int t = 0; t < 8; ++t) {
            s[t] += __shfl_xor(s[t], off);
            ss[t] += __shfl_xor(ss[t], off);
        }
    }
#pragma unroll
    for (int t = 0; t < 8; ++t) {
        const float mean = s[t] * (1.f / CDIM);
        const float rstd = rsqrtf(ss[t] * (1.f / CDIM) - mean * mean + 1e-5f);
        const int trow = (wv * 8 + t) * 384;
#pragma unroll
        for (int i = 0; i < 6; ++i) {
            const int c = lane + i * 64;
            tile[trow + c] = f2bf((v[i][t] - mean) * rstd * g[i] + be[i]);
        }
    }
    __syncthreads();
    uint4* dst = (uint4*)(Tn + ((size_t)b * 4096 + tile0) * CDIM);
    const uint4* srcp = (const uint4*)tile;
#pragma unroll
    for (int k = 0; k < 6; ++k)
        dst[k * 256 + threadIdx.x] = srcp[k * 256 + threadIdx.x];
}

// ---------------------------------------------------------------------------
// Tiled fp32 GEMM for dt_proj (K=24), NT, bias+softplus, bf16 store.
// ---------------------------------------------------------------------------
__global__ __launch_bounds__(256)
void gemm_dtproj_kernel(const float* __restrict__ A, const float* __restrict__ B,
                        ushort_t* __restrict__ C, const float* __restrict__ bias,
                        int M, int N, int K, int lda, int ldb, int ldc) {
    __shared__ __align__(16) float As[16][132];
    __shared__ __align__(16) float Bs[16][68];
    const int t = threadIdx.x;
    const int m0 = blockIdx.y * 128;
    const int n0 = blockIdx.x * 64;

    float acc[8][4];
#pragma unroll
    for (int i = 0; i < 8; ++i)
#pragma unroll
        for (int j = 0; j < 4; ++j) acc[i][j] = 0.f;

    const int mr = (t & 15) * 8;
    const int nr = (t >> 4) * 4;

    for (int k0 = 0; k0 < K; k0 += 16) {
#pragma unroll
        for (int idx = 0; idx < 8; ++idx) {
            const int e = idx * 256 + t;
            const int k = e & 15, m = e >> 4;
            float v = 0.f;
            if (k0 + k < K) v = A[(size_t)(m0 + m) * lda + (k0 + k)];
            As[k][m] = v;
        }
#pragma unroll
        for (int idx = 0; idx < 4; ++idx) {
            const int e = idx * 256 + t;
            const int k = e & 15, n = e >> 4;
            float v = 0.f;
            if ((n0 + n) < N && (k0 + k) < K) v = B[(size_t)(n0 + n) * ldb + (k0 + k)];
            Bs[k][n] = v;
        }
        __syncthreads();
#pragma unroll
        for (int k = 0; k < 16; ++k) {
            float4 a0 = *(const float4*)&As[k][mr];
            float4 a1 = *(const float4*)&As[k][mr + 4];
            float4 b0 = *(const float4*)&Bs[k][nr];
            const float av[8] = {a0.x, a0.y, a0.z, a0.w, a1.x, a1.y, a1.z, a1.w};
            const float bv[4] = {b0.x, b0.y, b0.z, b0.w};
#pragma unroll
            for (int i = 0; i < 8; ++i)
#pragma unroll
                for (int j = 0; j < 4; ++j)
                    acc[i][j] = fmaf(av[i], bv[j], acc[i][j]);
        }
        __syncthreads();
    }

#pragma unroll
    for (int i = 0; i < 8; ++i) {
        const int m = m0 + mr + i;
#pragma unroll
        for (int j = 0; j < 4; ++j) {
            const int n = n0 + nr + j;
            if (n >= N) continue;
            float v = acc[i][j] + bias[n];
            v = (v > 20.f) ? v : log1pf(__expf(v));
            C[(size_t)m * ldc + n] = f2bf(v);
        }
    }
}

// ---------------------------------------------------------------------------
// Causal depthwise conv1d (K=4) + bias + SiLU, bf16 in/out. 4 tokens/thread.
// ---------------------------------------------------------------------------
__global__ __launch_bounds__(256)
void dwconv_silu_kernel(const ushort_t* __restrict__ Xin, const float* __restrict__ W,
                        const float* __restrict__ bias, ushort_t* __restrict__ U) {
    const int dch = blockIdx.x * 256 + threadIdx.x;
    const int l0 = blockIdx.y * 4, b = blockIdx.z;
    const float4 w4 = ((const float4*)W)[dch];
    const float wk[4] = {w4.x, w4.y, w4.z, w4.w};
    const float bs = bias[dch];
    const size_t base = ((size_t)b * 4096 + l0) * DINC + dch;
    float r[7];
#pragma unroll
    for (int k = 0; k < 7; ++k) {
        const int ll = l0 - 3 + k;
        r[k] = (ll >= 0) ? bf2f(Xin[base + (size_t)(k - 3) * DINC]) : 0.f;
    }
#pragma unroll
    for (int j = 0; j < 4; ++j) {
        float acc = bs;
#pragma unroll
        for (int k = 0; k < 4; ++k) acc = fmaf(r[j + k], wk[k], acc);
        U[base + (size_t)j * DINC] = f2bf(acc / (1.f + __expf(-acc)));
    }
}

// ---------------------------------------------------------------------------
// Chunked parallel selective scan (3 phases). dt/u/z/y bf16; B,C fp32.
// ---------------------------------------------------------------------------
__global__ __launch_bounds__(256)
void scan_phase1_kernel(const ushort_t* __restrict__ DT, const ushort_t* __restrict__ U,
                        const float* __restrict__ DBL, const float* __restrict__ A_log,
                        float* __restrict__ HOUT, float* __restrict__ SDT) {
    const int b = blockIdx.z, chunk = blockIdx.y;
    const int dch = blockIdx.x * 256 + threadIdx.x;
    float Arow[16];
#pragma unroll
    for (int n = 0; n < NST; ++n) Arow[n] = -__expf(A_log[dch * NST + n]);

    __shared__ float bcs[LCHUNK][16];
    const size_t tokbase = (size_t)b * 4096 + chunk * LCHUNK;
#pragma unroll
    for (int idx = 0; idx < 4; ++idx) {
        const int e = idx * 256 + threadIdx.x;
        bcs[e >> 4][e & 15] = DBL[(tokbase + (e >> 4)) * 56 + 24 + (e & 15)];
    }
    __syncthreads();

    size_t off = tokbase * DINC + dch;
    float h[16];
#pragma unroll
    for (int n = 0; n < NST; ++n) h[n] = 0.f;
    float sdt = 0.f;
    float cdt = bf2f(DT[off]), cu = bf2f(U[off]);
    for (int t = 0; t < LCHUNK; ++t) {
        float ndt = 0.f, nu = 0.f;
        if (t < LCHUNK - 1) { ndt = bf2f(DT[off + DINC]); nu = bf2f(U[off + DINC]); }
        sdt += cdt;
        const float du = cdt * cu;
#pragma unroll
        for (int n = 0; n < NST; ++n)
            h[n] = __expf(cdt * Arow[n]) * h[n] + du * bcs[t][n];
        off += DINC;
        cdt = ndt; cu = nu;
    }
    float* hp = HOUT + (((size_t)(b * DINC + dch) * NCHUNK + chunk) << 4);
#pragma unroll
    for (int n = 0; n < NST; ++n) hp[n] = h[n];
    SDT[(size_t)(b * DINC + dch) * NCHUNK + chunk] = sdt;
}

__global__ __launch_bounds__(256)
void scan_phase2_kernel(float* __restrict__ HOUT, const float* __restrict__ SDT,
                        const float* __restrict__ A_log) {
    const int t = blockIdx.x * 256 + threadIdx.x;        // 49152
    const int b = t / (DINC * NST);
    const int rem = t - b * (DINC * NST);
    const int d = rem >> 4, n = rem & 15;
    const float An = -__expf(A_log[d * NST + n]);
    float* hp = HOUT + (((size_t)(b * DINC + d) * NCHUNK) << 4) + n;
    const float* sp = SDT + (size_t)(b * DINC + d) * NCHUNK;
    float H = 0.f;
    for (int c = 0; c < NCHUNK; ++c) {
        const float tmp = hp[c * 16];
        const float dA = __expf(An * sp[c]);
        hp[c * 16] = H;
        H = dA * H + tmp;
    }
}

__global__ __launch_bounds__(256)
void scan_phase3_kernel(ushort_t* __restrict__ DT, const ushort_t* __restrict__ U,
                        const float* __restrict__ DBL, const ushort_t* __restrict__ Z,
                        const float* __restrict__ A_log, const float* __restrict__ D_skip,
                        const float* __restrict__ HOUT) {
    const int b = blockIdx.z, chunk = blockIdx.y;
    const int dch = blockIdx.x * 256 + threadIdx.x;
    float Arow[16];
#pragma unroll
    for (int n = 0; n < NST; ++n) Arow[n] = -__expf(A_log[dch * NST + n]);
    const float Dsk = D_skip[dch];

    __shared__ float bcs[LCHUNK][32];
    const size_t tokbase = (size_t)b * 4096 + chunk * LCHUNK;
#pragma unroll
    for (int idx = 0; idx < 8; ++idx) {
        const int e = idx * 256 + threadIdx.x;
        bcs[e >> 5][e & 31] = DBL[(tokbase + (e >> 5)) * 56 + 24 + (e & 31)];
    }
    __syncthreads();

    float h[16];
    const float* hp = HOUT + (((size_t)(b * DINC + dch) * NCHUNK + chunk) << 4);
#pragma unroll
    for (int n = 0; n < NST; ++n) h[n] = hp[n];

    size_t off = tokbase * DINC + dch;
    float cdt = bf2f(DT[off]), cu = bf2f(U[off]), cz = bf2f(Z[off]);
    for (int t = 0; t < LCHUNK; ++t) {
        float ndt = 0.f, nu = 0.f, nz = 0.f;
        if (t < LCHUNK - 1) {
            ndt = bf2f(DT[off + DINC]); nu = bf2f(U[off + DINC]); nz = bf2f(Z[off + DINC]);
        }
        const float du = cdt * cu;
        float y = 0.f;
#pragma unroll
        for (int n = 0; n < NST; ++n) {
            h[n] = __expf(cdt * Arow[n]) * h[n] + du * bcs[t][n];
            y = fmaf(h[n], bcs[t][16 + n], y);
        }
        y += cu * Dsk;
        const float sz = cz / (1.f + __expf(-cz));
        DT[off] = f2bf(y * sz);
        off += DINC;
        cdt = ndt; cu = nu; cz = nz;
    }
}

// ---------------------------------------------------------------------------
extern "C" void kernel_launch(void* const* d_in, const int* in_sizes, int n_in,
                              void* d_out, int out_size, void* d_ws, size_t ws_size,
                              hipStream_t stream) {
    (void)in_sizes; (void)n_in; (void)out_size; (void)ws_size;
    const float* x         = (const float*)d_in[0];
    const float* w1        = (const float*)d_in[1];
    const float* w2        = (const float*)d_in[3];
    const float* w3        = (const float*)d_in[5];
    const float* w4        = (const float*)d_in[7];
    const float* ln_g      = (const float*)d_in[9];
    const float* ln_b      = (const float*)d_in[10];
    const float* in_proj_w = (const float*)d_in[11];
    const float* conv1d_w  = (const float*)d_in[12];
    const float* conv1d_b  = (const float*)d_in[13];
    const float* x_proj_w  = (const float*)d_in[14];
    const float* dt_proj_w = (const float*)d_in[15];
    const float* dt_proj_b = (const float*)d_in[16];
    const float* A_log     = (const float*)d_in[17];
    const float* D_skip    = (const float*)d_in[18];
    const float* out_proj_w= (const float*)d_in[19];
    float* out = (float*)d_out;

    // Workspace regions (floats): R0..R4. Lifetimes disjoint where aliased.
    float* ws = (float*)d_ws;
    float* R0 = ws;                    //  6291456
    float* R1 = ws + 6291456;          //  6291456
    float* R2 = ws + 12582912;         // 12582912
    float* R3 = ws + 25165824;         // 12582912
    float* R4 = ws + 37748736;         // 12582912

    // GSC-phase aliases (conv partials/outputs bf16)
    ushort_t* P0    = (ushort_t*)R0;                 // partial z=0
    ushort_t* P1    = P0 + PSTRIDE;                  // partial z=1
    ushort_t* C34   = (ushort_t*)R3;                 // c3/c4 outputs bf16
    ushort_t* Wb1   = (ushort_t*)R2;                 // 3981312 bf16
    ushort_t* Xp    = (ushort_t*)(R2 + 2097152);     // 8957952 bf16
    ushort_t* w3b   = (ushort_t*)(R2 + 6576128);     // 147456 bf16
    ushort_t* w4b   = (ushort_t*)(R2 + 6649856);     // 147456 bf16
    ushort_t* Wb2   = (ushort_t*)(R2 + 6723584);     // 3981312 bf16
    float*    SA    = R4;                            // stats A
    float*    SB    = R4 + 4096;                     // stats B
    ushort_t* ipwb  = (ushort_t*)(R4 + 6291456);
    ushort_t* opwb  = (ushort_t*)(R4 + 6586368);
    ushort_t* xpwb  = (ushort_t*)(R4 + 6733824);
    // Mamba-phase aliases
    ushort_t* tnb   = (ushort_t*)R0;                 // 16384*384 bf16
    float*    DBL   = R0 + 3145728;                  // 16384*56 fp32
    float*    HOUT  = R1;
    float*    SDT   = R1 + 3145728;
    ushort_t* XIN   = (ushort_t*)R2;
    ushort_t* Zb    = (ushort_t*)R3;
    ushort_t* Ub    = (ushort_t*)R4;
    ushort_t* DTb   = (ushort_t*)R2;

    const size_t XP_BYTES = (size_t)4 * 18 * 18 * 18 * CDIM * 2;

    // ---- upfront: zero pad borders, convert all weights, pad x ----
    hipMemsetAsync(Xp, 0, XP_BYTES, stream);
    prep_weights_kernel<<<2346, 256, 0, stream>>>(
        w1, w2, w3, w4, in_proj_w, out_proj_w, x_proj_w,
        Wb1, Wb2, w3b, w4b, ipwb, opwb, xpwb);
    pad_kernel<<<1024, 384, 0, stream>>>(x, Xp);
    // ---- c1 (3x3x3 z-split) + c3 (1x1) fused; 512-thread 128x256 blocks ----
    conv_kernel<1><<<576, 512, 0, stream>>>(Xp, Wb1, w3b, P0, C34);
    inorm_stats_combo_kernel<<<3072, 256, 0, stream>>>(P0, P1, SA, C34, SB);
    pad_fuse2_kernel<<<1024, 384, 0, stream>>>(P0, P1, SA, Xp);             // x1a
    // ---- c2 ----
    conv_kernel<0><<<384, 512, 0, stream>>>(Xp, Wb2, nullptr, P0, nullptr);
    inorm_stats_combo_kernel<<<1536, 256, 0, stream>>>(P0, P1, SA, nullptr, nullptr);
    pad_fuse3_kernel<<<1024, 384, 0, stream>>>(P0, P1, SA, C34, SB, Xp);    // S
    // ---- c4 (1x1) ----
    conv_kernel<2><<<192, 512, 0, stream>>>(Xp, nullptr, w4b, nullptr, C34);
    inorm_stats_kernel<<<1536, 256, 0, stream>>>(C34, SA);
    // ---- fused relu(IN(c4)) + x residual + LayerNorm -> tn bf16 [b][l][c]
    layernorm_kernel<<<512, 256, 0, stream>>>(C34, SA, x, ln_g, ln_b, tnb);
    // ---- in_proj (bf16 MFMA, gl_lds+prefetch): tn x W^T -> XIN | Zb (bf16)
    gemm_gl_kernel<1><<<1536, 256, 0, stream>>>(
        tnb, ipwb, XIN, Zb, 16384, 1536, CDIM, 0, 12);
    // ---- causal depthwise conv + SiLU -> Ub (bf16)
    dwconv_silu_kernel<<<dim3(3, 1024, 4), 256, 0, stream>>>(XIN, conv1d_w, conv1d_b, Ub);
    // ---- x_proj (bf16 MFMA, N=56 masked): u x W^T -> DBL (fp32)
    gemm_gl_kernel<0><<<128, 256, 0, stream>>>(
        Ub, xpwb, DBL, nullptr, 16384, 56, DINC, 56, 1);
    // ---- dt_proj (fp32 VALU, K=24) + bias + softplus -> DTb (bf16)
    gemm_dtproj_kernel<<<dim3(12, 128), 256, 0, stream>>>(
        DBL, dt_proj_w, DTb, dt_proj_b, 16384, DINC, 24, 56, 24, DINC);
    // ---- chunked parallel selective scan (y bf16 over DTb)
    scan_phase1_kernel<<<dim3(3, NCHUNK, 4), 256, 0, stream>>>(
        DTb, Ub, DBL, A_log, HOUT, SDT);
    scan_phase2_kernel<<<192, 256, 0, stream>>>(HOUT, SDT, A_log);
    scan_phase3_kernel<<<dim3(3, NCHUNK, 4), 256, 0, stream>>>(
        DTb, Ub, DBL, Zb, A_log, D_skip, HOUT);
    // ---- out_proj (bf16 MFMA) -> d_out transposed fp32
    gemm_gl_kernel<2><<<384, 256, 0, stream>>>(
        DTb, opwb, out, nullptr, 16384, CDIM, DINC, 0, 3);
}